// Round 13
// baseline (187.297 us; speedup 1.0000x reference)
//
#include <hip/hip_runtime.h>
#include <hip/hip_bf16.h>

#define NTOK 98
#define CDIM 128
#define SCALE 0.17677669529663687f
#define LOG2E 1.4426950408889634f
#define NEG_BIG -1e30f
#define CMBW 112   // cmb row width: covers full fragment n-range 0..111

typedef short bf16x8 __attribute__((ext_vector_type(8)));
typedef short bf16x4 __attribute__((ext_vector_type(4)));
typedef float f32x4 __attribute__((ext_vector_type(4)));

#define MFMA32(a,b,c) __builtin_amdgcn_mfma_f32_16x16x32_bf16(a,b,c,0,0,0)

#if __has_builtin(__builtin_amdgcn_mfma_f32_16x16x16_bf16)
#define MFMA16(a,b,c) __builtin_amdgcn_mfma_f32_16x16x16_bf16(a,b,c,0,0,0)
#elif __has_builtin(__builtin_amdgcn_mfma_f32_16x16x16bf16_1k)
#define MFMA16(a,b,c) __builtin_amdgcn_mfma_f32_16x16x16bf16_1k(a,b,c,0,0,0)
#else
__device__ __forceinline__ f32x4 mfma16_asm(bf16x4 a, bf16x4 b, f32x4 c) {
  asm("v_mfma_f32_16x16x16_bf16 %0, %1, %2, %0" : "+v"(c) : "v"(a), "v"(b));
  return c;
}
#define MFMA16(a,b,c) mfma16_asm(a,b,c)
#endif

#if __has_builtin(__builtin_amdgcn_exp2f)
#define EXP2F(x) __builtin_amdgcn_exp2f(x)
#else
#define EXP2F(x) exp2f(x)
#endif
#if __has_builtin(__builtin_amdgcn_rcpf)
#define RCPF(x) __builtin_amdgcn_rcpf(x)
#else
#define RCPF(x) (1.f / (x))
#endif

__device__ __forceinline__ unsigned short f2bf(float f) {
  __hip_bfloat16 h = __float2bfloat16(f);
  unsigned short u;
  __builtin_memcpy(&u, &h, 2);
  return u;
}
__device__ __forceinline__ float bf2f(unsigned short b) {
  union { unsigned u; float f; } v; v.u = ((unsigned)b) << 16; return v.f;
}
// 4x f32 -> bf16x4 via packed cvt pairs (memcpy: __hip_bfloat162 not trivially copyable)
__device__ __forceinline__ bf16x4 cvt4(f32x4 v) {
  __hip_bfloat162 a = __float22bfloat162_rn(make_float2(v[0], v[1]));
  __hip_bfloat162 b = __float22bfloat162_rn(make_float2(v[2], v[3]));
  bf16x4 r;
  __builtin_memcpy(&r, &a, 4);
  __builtin_memcpy(((char*)&r) + 4, &b, 4);
  return r;
}

// stride-128 xs tile: XOR elem bits 3..5 by row (b64/b128-safe; kills 256B-stride conflicts)
__device__ __forceinline__ int swzK(int row, int col) {
  return row * 128 + (col ^ ((row & 7) << 3));
}
// stride-64 k tile: same XOR; col<64 so bits 3..5 stay in-row; b64-safe
__device__ __forceinline__ int swz64(int row, int col) {
  return row * 64 + (col ^ ((row & 7) << 3));
}

__device__ __forceinline__ bf16x8 ldfrag(const float* __restrict__ p) {
  float4 a = *(const float4*)p;
  float4 b = *(const float4*)(p + 4);
  bf16x8 fr;
  fr[0]=(short)f2bf(a.x); fr[1]=(short)f2bf(a.y); fr[2]=(short)f2bf(a.z); fr[3]=(short)f2bf(a.w);
  fr[4]=(short)f2bf(b.x); fr[5]=(short)f2bf(b.y); fr[6]=(short)f2bf(b.z); fr[7]=(short)f2bf(b.w);
  return fr;
}

__device__ __forceinline__ int pcode(int t) {       // rel-pos code
  int d = t / 49, r = t % 49;
  return d * 169 + (r / 7) * 13 + (r % 7);
}

// weight fragment accessor (qkv row-tile t, k-chunk kk)
template<bool PRE>
__device__ __forceinline__ bf16x8 wfrag(const unsigned short* __restrict__ qpre,
                                        const float* __restrict__ qkv_w,
                                        int lane, int lm, int lg, int t, int kk) {
  if constexpr (PRE) return *(const bf16x8*)&qpre[(size_t)((t * 4 + kk) * 64 + lane) * 8];
  else return ldfrag(qkv_w + (size_t)(t * 16 + lm) * CDIM + kk * 32 + lg * 8);
}

// stage k/v for head-group g: waves 0-3 -> k [98][64] (swapped), 4-7 -> v^T [64][100]
// R13: __forceinline__ free function (R12's plain lambda was NOT inlined ->
// stack frame in scratch: VGPR 40, +66 MB FETCH, +168 MB WRITE).
template<bool PRE>
__device__ __forceinline__ void stage_kv_f(
    int g, int wv, int lane, int lm, int lg,
    const unsigned short* __restrict__ xs,
    unsigned short* __restrict__ kbuf, unsigned short* __restrict__ vbuf,
    const unsigned short* __restrict__ qpre, const float* __restrict__ qkv_w,
    const float* __restrict__ bias)
{
  if (wv < 4) {
    bf16x8 Bk[4];
#pragma unroll
    for (int kk = 0; kk < 4; ++kk) Bk[kk] = wfrag<PRE>(qpre, qkv_w, lane, lm, lg, 8 + g * 4 + wv, kk);
    const float4 bk4 = *(const float4*)(bias + CDIM + g * 64 + wv * 16 + lg * 4);
    for (int mi = 0; mi < 7; ++mi) {
      int arow = mi * 16 + lm; if (arow > 97) arow = 97;
      bf16x8 A[4];
#pragma unroll
      for (int kk = 0; kk < 4; ++kk) A[kk] = *(const bf16x8*)&xs[swzK(arow, kk * 32 + lg * 8)];
      f32x4 ak = {0.f,0.f,0.f,0.f};
#pragma unroll
      for (int kk = 0; kk < 4; ++kk) ak = MFMA32(Bk[kk], A[kk], ak);  // swapped
      int ktok = mi * 16 + lm;
      if (ktok < NTOK) {
        f32x4 t;
#pragma unroll
        for (int r = 0; r < 4; ++r) t[r] = ak[r] + ((const float*)&bk4)[r];
        *(bf16x4*)&kbuf[swz64(ktok, wv * 16 + lg * 4)] = cvt4(t);
      }
    }
  } else {
    bf16x8 Bv[4];
#pragma unroll
    for (int kk = 0; kk < 4; ++kk) Bv[kk] = wfrag<PRE>(qpre, qkv_w, lane, lm, lg, 16 + g * 4 + (wv - 4), kk);
    const float bv_ = bias[2 * CDIM + g * 64 + (wv - 4) * 16 + lm];
    for (int mi = 0; mi < 7; ++mi) {
      int arow = mi * 16 + lm; if (arow > 97) arow = 97;
      bf16x8 A[4];
#pragma unroll
      for (int kk = 0; kk < 4; ++kk) A[kk] = *(const bf16x8*)&xs[swzK(arow, kk * 32 + lg * 8)];
      f32x4 av = {0.f,0.f,0.f,0.f};
#pragma unroll
      for (int kk = 0; kk < 4; ++kk) av = MFMA32(A[kk], Bv[kk], av);  // normal
      int vtok0 = mi * 16 + lg * 4;
      if (vtok0 < 100) {                             // toks 98..99: finite pad data
        f32x4 t;
#pragma unroll
        for (int r = 0; r < 4; ++r) t[r] = av[r] + bv_;
        *(bf16x4*)&vbuf[(size_t)((wv - 4) * 16 + lm) * 100 + vtok0] = cvt4(t);
      }
    }
  }
}

// attention for one unit; outputs two normalized o fragments (named refs, no
// pointer-to-local across call boundary)
template<bool PRE>
__device__ __forceinline__ void attn_unit_f(
    int mi, int hh, int h, int lm, int lg, int wmod,
    bf16x4 bq0, bf16x4 bq1,
    const unsigned short* __restrict__ kbuf, const unsigned short* __restrict__ vbuf,
    const float* __restrict__ cmb, const float* __restrict__ maskw,
    const unsigned short* __restrict__ rpbL, const short* __restrict__ mcode,
    bf16x4& og0, bf16x4& og1)
{
  const int cbl = hh * 32;
  f32x4 s[7];
  __builtin_amdgcn_s_setprio(1);
#pragma unroll
  for (int nj = 0; nj < 7; ++nj) {                   // QK^T swapped: col=m(lm), row=n
    int krow = nj * 16 + lm; if (krow > 97) krow = 97;
    bf16x4 k0 = *(const bf16x4*)&kbuf[swz64(krow, cbl + lg * 4)];
    bf16x4 k1 = *(const bf16x4*)&kbuf[swz64(krow, cbl + 16 + lg * 4)];
    f32x4 z = {0.f,0.f,0.f,0.f};
    z = MFMA16(k0, bq0, z);
    s[nj] = MFMA16(k1, bq1, z);
  }
  __builtin_amdgcn_s_setprio(0);
  const int m = mi * 16 + lm;
  const int mclamp = m > 97 ? 97 : m;
  float sum = 0.f;
  if constexpr (PRE) {
    const float* __restrict__ cp =
        cmb + ((size_t)(wmod * 4 + h) * NTOK + mclamp) * CMBW + lg * 4;
#pragma unroll
    for (int nj = 0; nj < 7; ++nj) {
      float4 cv = *(const float4*)(cp + nj * 16);
#pragma unroll
      for (int r = 0; r < 4; ++r) {
        float e = EXP2F(s[nj][r] + ((const float*)&cv)[r]);  // no-max softmax
        s[nj][r] = e; sum += e;
      }
    }
  } else {
    const int cm4 = ((int)mcode[mclamp]) * 4 + h + 1012;
    const float* __restrict__ mrow = maskw + mclamp * NTOK;
#pragma unroll
    for (int nj = 0; nj < 7; ++nj) {
      const int n0 = nj * 16 + lg * 4;
#pragma unroll
      for (int r = 0; r < 4; ++r) {
        int n = n0 + r;
        float val = NEG_BIG;
        if (n < NTOK)
          val = s[nj][r] + (mrow[n] + bf2f(rpbL[cm4 - ((int)mcode[n]) * 4])) * LOG2E;
        float e = EXP2F(val);
        s[nj][r] = e; sum += e;
      }
    }
  }
  sum += __shfl_xor(sum, 16);
  sum += __shfl_xor(sum, 32);
  const float inv = RCPF(sum);
  float invr[4];
#pragma unroll
  for (int r = 0; r < 4; ++r) invr[r] = __shfl(inv, lg * 4 + r);
  bf16x4 pp[7];                                      // unnormalized P A-frags
#pragma unroll
  for (int nj = 0; nj < 7; ++nj) pp[nj] = cvt4(s[nj]);
#pragma unroll
  for (int dt = 0; dt < 2; ++dt) {
    const int dl = cbl + dt * 16 + lm;               // local chan in group
    f32x4 acc = {0.f,0.f,0.f,0.f};
    __builtin_amdgcn_s_setprio(1);
#pragma unroll
    for (int nj = 0; nj < 7; ++nj) {
      const int vc = nj < 6 ? nj * 16 + lg * 4 : 96;         // clamp: P=0 there
      bf16x4 bv = *(const bf16x4*)&vbuf[(size_t)dl * 100 + vc];
      acc = MFMA16(pp[nj], bv, acc);
    }
    __builtin_amdgcn_s_setprio(0);
    f32x4 t;
#pragma unroll
    for (int r = 0; r < 4; ++r) t[r] = acc[r] * invr[r];
    if (dt == 0) og0 = cvt4(t); else og1 = cvt4(t);
  }
}

__device__ __forceinline__ void write_o_f(
    int mi, int hh, int g, int lm, int lg,
    unsigned short* __restrict__ xs, bf16x4 og0, bf16x4 og1)
{
#pragma unroll
  for (int dt = 0; dt < 2; ++dt) {
    const int d = (2 * g + hh) * 32 + dt * 16 + lm;
    const bf16x4 og = dt == 0 ? og0 : og1;
#pragma unroll
    for (int r = 0; r < 4; ++r) {
      int m2 = mi * 16 + lg * 4 + r;
      if (m2 < NTOK) xs[swzK(m2, d)] = (unsigned short)og[r];
    }
  }
}

// ---------------- prep 1: weights -> bf16 fragment-order (q: SCALE*LOG2E folded) ----------------
__global__ __launch_bounds__(512)
void prep_w(const float* __restrict__ qkv_w, const float* __restrict__ qkv_b,
            const float* __restrict__ proj_w, const float* __restrict__ proj_b,
            unsigned short* __restrict__ qpre, unsigned short* __restrict__ ppre,
            float* __restrict__ bpre)
{
  int gid = blockIdx.x * 512 + threadIdx.x;
  if (gid < 6144) {                                  // qkv: 24 row-tiles x 4 kk x 64 lanes
    int t = gid >> 8, rem = gid & 255, kk = rem >> 6, ln = rem & 63;
    int row = t * 16 + (ln & 15), col = kk * 32 + (ln >> 4) * 8;
    float sc = (row < CDIM) ? SCALE * LOG2E : 1.f;   // fold scale*log2e into Wq
    const float* s = qkv_w + (size_t)row * CDIM + col;
    unsigned short* d = qpre + (size_t)gid * 8;
#pragma unroll
    for (int e = 0; e < 8; ++e) d[e] = f2bf(s[e] * sc);
  } else if (gid < 8192) {                           // proj: 8 row-tiles
    int f2 = gid - 6144;
    int t = f2 >> 8, rem = f2 & 255, kk = rem >> 6, ln = rem & 63;
    const float* s = proj_w + (size_t)(t * 16 + (ln & 15)) * CDIM + kk * 32 + (ln >> 4) * 8;
    unsigned short* d = ppre + (size_t)f2 * 8;
#pragma unroll
    for (int e = 0; e < 8; ++e) d[e] = f2bf(s[e]);
  } else {                                           // biases (512 values)
    int i = gid - 8192;
    if (i < 384) bpre[i] = qkv_b[i] * (i < CDIM ? SCALE * LOG2E : 1.f);
    else if (i < 512) bpre[i] = proj_b[i - 384];
  }
}

// ---------------- prep 2: cmb[w][h][m][0..111] = (mask + rpb)*LOG2E (pads = -1e30) ----------------
__global__ __launch_bounds__(256)
void prep_cmb(const float* __restrict__ mask, const float* __restrict__ rpb,
              float* __restrict__ cmb, int nW)
{
  const int total = 256 * NTOK * CMBW;               // (w,h) x m x n-padded
  for (int idx = blockIdx.x * 256 + threadIdx.x; idx < total; idx += gridDim.x * 256) {
    int row = idx / CMBW, n = idx - row * CMBW;
    int wh = row / NTOK, m = row - wh * NTOK;
    int w = wh >> 2, h = wh & 3;
    float v = NEG_BIG;
    if (n < NTOK)
      v = (mask[((size_t)w * NTOK + m) * NTOK + n]
           + rpb[(pcode(m) - pcode(n) + 253) * 4 + h]) * LOG2E;
    cmb[idx] = v;
  }
}

// ---------------- main kernel ----------------
// R13 = R12 (3 blocks/CU: 50 KB LDS via per-head-group k/v staging) with the
// helper lambdas converted to __forceinline__ functions (fixes R12's
// non-inlined-call scratch traffic).
template<bool PRE>
__global__ __launch_bounds__(512, 6)
void win_attn(const float* __restrict__ x, const float* __restrict__ mask,
              const float* __restrict__ qkv_w, const float* __restrict__ qkv_b,
              const float* __restrict__ rpb, const float* __restrict__ proj_w,
              const float* __restrict__ proj_b, float* __restrict__ out, int nW,
              const float* __restrict__ cmb, const unsigned short* __restrict__ qpre,
              const unsigned short* __restrict__ ppre, const float* __restrict__ bpre)
{
  __shared__ __align__(16) unsigned short xs[98 * 128];   // x; later o overlay
  __shared__ __align__(16) unsigned short kbuf[98 * 64];  // k for current head-group
  __shared__ __align__(16) unsigned short vbuf[64 * 100]; // v^T for current head-group
  __shared__ unsigned short rpbL[PRE ? 2 : 2028];
  __shared__ short mcode[PRE ? 2 : 112];

  const int tid = threadIdx.x;
  const int lane = tid & 63;
  const int wv = tid >> 6;
  const int lm = lane & 15;
  const int lg = lane >> 4;
  const int blk = blockIdx.x;
  const int wmod = blk % nW;
  const float* __restrict__ xblk = x + (size_t)blk * (NTOK * CDIM);
  const float* __restrict__ maskw = mask + (size_t)wmod * (NTOK * NTOK);
  const float* __restrict__ bias = PRE ? bpre : qkv_b;

  if constexpr (!PRE) {
    if (tid < 112) mcode[tid] = (short)(tid < NTOK ? pcode(tid) : 0);
    for (int i = tid; i < 2028; i += 512) rpbL[i] = f2bf(rpb[i]);
  }
  for (int v = tid; v < NTOK * 32; v += 512) {       // stage x -> xs (bf16, swizzled)
    int row = v >> 5, c4 = (v & 31) << 2;
    float4 f = *(const float4*)(xblk + row * CDIM + c4);
    f32x4 fv; fv[0]=f.x; fv[1]=f.y; fv[2]=f.z; fv[3]=f.w;
    *(bf16x4*)&xs[swzK(row, c4)] = cvt4(fv);
  }
  __syncthreads();

  const bool have1 = (wv < 6);
  const int hh0 = wv / 7, mi0 = wv % 7;
  const int mi1 = wv + 1;                            // unit u1: hh=1 (when wv<6)

  // ---- phase 1: k0/v0 staging + q (both groups) -> regs ----
  stage_kv_f<PRE>(0, wv, lane, lm, lg, xs, kbuf, vbuf, qpre, qkv_w, bias);
  bf16x4 bq[2][2][2];                                // [j][g][ct]
#pragma unroll
  for (int j = 0; j < 2; ++j) {
    if (j == 0 || have1) {
      const int mi = j ? mi1 : mi0, hh = j ? 1 : hh0;
      int arow = mi * 16 + lm; if (arow > 97) arow = 97;
      bf16x8 Xf[4];
#pragma unroll
      for (int kk = 0; kk < 4; ++kk) Xf[kk] = *(const bf16x8*)&xs[swzK(arow, kk * 32 + lg * 8)];
#pragma unroll
      for (int g = 0; g < 2; ++g) {
        const int h = 2 * g + hh;
#pragma unroll
        for (int ct = 0; ct < 2; ++ct) {
          const int t = h * 2 + ct;
          f32x4 acc = {0.f,0.f,0.f,0.f};
#pragma unroll
          for (int kk = 0; kk < 4; ++kk)
            acc = MFMA32(wfrag<PRE>(qpre, qkv_w, lane, lm, lg, t, kk), Xf[kk], acc);
          const float4 qb4 = *(const float4*)(bias + t * 16 + lg * 4);
          f32x4 tq;
#pragma unroll
          for (int r = 0; r < 4; ++r) {
            float vq = acc[r] + ((const float*)&qb4)[r];
            if constexpr (!PRE) vq *= SCALE * LOG2E;
            tq[r] = vq;
          }
          bq[j][g][ct] = cvt4(tq);
        }
      }
    }
  }
  __syncthreads();

  // ---- attention g=0: hold o in regs (xs still needed by g=1 staging) ----
  bf16x4 o00a, o00b, o01a, o01b;
  attn_unit_f<PRE>(mi0, hh0, hh0, lm, lg, wmod, bq[0][0][0], bq[0][0][1],
                   kbuf, vbuf, cmb, maskw, rpbL, mcode, o00a, o00b);
  if (have1)
    attn_unit_f<PRE>(mi1, 1, 1, lm, lg, wmod, bq[1][0][0], bq[1][0][1],
                     kbuf, vbuf, cmb, maskw, rpbL, mcode, o01a, o01b);
  __syncthreads();   // kbuf/vbuf reads done -> restage

  stage_kv_f<PRE>(1, wv, lane, lm, lg, xs, kbuf, vbuf, qpre, qkv_w, bias);
  __syncthreads();   // staging done; xs now dead -> o overlay ok

  // ---- drop held o(g=0), then attention g=1 writes o directly ----
  write_o_f(mi0, hh0, 0, lm, lg, xs, o00a, o00b);
  if (have1) write_o_f(mi1, 1, 0, lm, lg, xs, o01a, o01b);
  {
    bf16x4 ta, tb;
    attn_unit_f<PRE>(mi0, hh0, 2 + hh0, lm, lg, wmod, bq[0][1][0], bq[0][1][1],
                     kbuf, vbuf, cmb, maskw, rpbL, mcode, ta, tb);
    write_o_f(mi0, hh0, 1, lm, lg, xs, ta, tb);
    if (have1) {
      attn_unit_f<PRE>(mi1, 1, 3, lm, lg, wmod, bq[1][1][0], bq[1][1][1],
                       kbuf, vbuf, cmb, maskw, rpbL, mcode, ta, tb);
      write_o_f(mi1, 1, 1, lm, lg, xs, ta, tb);
    }
  }
  __syncthreads();   // o complete

  // ---------------- GEMM3 (swapped): out = o @ Wp^T, float4 stores ----------------
  {
    bf16x8 Bp[4];
#pragma unroll
    for (int kk = 0; kk < 4; ++kk) {
      if constexpr (PRE) Bp[kk] = *(const bf16x8*)&ppre[(size_t)((wv * 4 + kk) * 64 + lane) * 8];
      else Bp[kk] = ldfrag(proj_w + (size_t)(wv * 16 + lm) * CDIM + kk * 32 + lg * 8);
    }
    const float4 pb4 = *(const float4*)((PRE ? bpre + 384 : proj_b) + wv * 16 + lg * 4);
    float* __restrict__ outb = out + (size_t)blk * (NTOK * CDIM);
    for (int mi = 0; mi < 7; ++mi) {
      int orow = mi * 16 + lm; if (orow > 97) orow = 97;
      f32x4 acc = {0.f,0.f,0.f,0.f};
#pragma unroll
      for (int kk = 0; kk < 4; ++kk) {
        bf16x8 Bo = *(const bf16x8*)&xs[swzK(orow, kk * 32 + lg * 8)];
        acc = MFMA32(Bp[kk], Bo, acc);               // row=out-chan, col=token
      }
      int tok = mi * 16 + lm;
      if (tok < NTOK) {
        float4 o4;
        o4.x = acc[0] + pb4.x; o4.y = acc[1] + pb4.y;
        o4.z = acc[2] + pb4.z; o4.w = acc[3] + pb4.w;
        *(float4*)(outb + (size_t)tok * CDIM + wv * 16 + lg * 4) = o4;
      }
    }
  }
}

extern "C" void kernel_launch(void* const* d_in, const int* in_sizes, int n_in,
                              void* d_out, int out_size, void* d_ws, size_t ws_size,
                              hipStream_t stream) {
  const float* x      = (const float*)d_in[0];
  const float* mask   = (const float*)d_in[1];
  const float* qkv_w  = (const float*)d_in[2];
  const float* qkv_b  = (const float*)d_in[3];
  const float* rpb    = (const float*)d_in[4];
  const float* proj_w = (const float*)d_in[5];
  const float* proj_b = (const float*)d_in[6];
  int B  = in_sizes[0] / (NTOK * CDIM);
  int nW = in_sizes[1] / (NTOK * NTOK);

  const size_t CMB_B  = (size_t)256 * NTOK * CMBW * 4;  // 11,239,424
  const size_t QPRE_B = 24 * 4 * 64 * 8 * 2;            // 98,304
  const size_t PPRE_B = 8 * 4 * 64 * 8 * 2;             // 32,768
  const size_t BIAS_B = 512 * 4;
  const size_t need = CMB_B + QPRE_B + PPRE_B + BIAS_B;

  if (ws_size >= need) {
    float* cmb = (float*)d_ws;
    unsigned short* qpre = (unsigned short*)((char*)d_ws + CMB_B);
    unsigned short* ppre = (unsigned short*)((char*)d_ws + CMB_B + QPRE_B);
    float* bpre = (float*)((char*)d_ws + CMB_B + QPRE_B + PPRE_B);
    hipLaunchKernelGGL(prep_w, dim3(17), dim3(512), 0, stream,
                       qkv_w, qkv_b, proj_w, proj_b, qpre, ppre, bpre);
    hipLaunchKernelGGL(prep_cmb, dim3(1024), dim3(256), 0, stream, mask, rpb, cmb, nW);
    hipLaunchKernelGGL(win_attn<true>, dim3(B), dim3(512), 0, stream,
                       x, mask, qkv_w, qkv_b, rpb, proj_w, proj_b, (float*)d_out, nW,
                       cmb, qpre, ppre, bpre);
  } else {
    hipLaunchKernelGGL(win_attn<false>, dim3(B), dim3(512), 0, stream,
                       x, mask, qkv_w, qkv_b, rpb, proj_w, proj_b, (float*)d_out, nW,
                       (const float*)nullptr, (const unsigned short*)nullptr,
                       (const unsigned short*)nullptr, (const float*)nullptr);
  }
}

// Round 14
// 137.981 us; speedup vs baseline: 1.3574x; 1.3574x over previous
//
#include <hip/hip_runtime.h>
#include <hip/hip_bf16.h>

#define NTOK 98
#define CDIM 128
#define SCALE 0.17677669529663687f
#define LOG2E 1.4426950408889634f
#define NEG_BIG -1e30f
#define CMBW 112   // cmb row width: covers full fragment n-range 0..111

typedef short bf16x8 __attribute__((ext_vector_type(8)));
typedef short bf16x4 __attribute__((ext_vector_type(4)));
typedef float f32x4 __attribute__((ext_vector_type(4)));

#define MFMA32(a,b,c) __builtin_amdgcn_mfma_f32_16x16x32_bf16(a,b,c,0,0,0)

#if __has_builtin(__builtin_amdgcn_mfma_f32_16x16x16_bf16)
#define MFMA16(a,b,c) __builtin_amdgcn_mfma_f32_16x16x16_bf16(a,b,c,0,0,0)
#elif __has_builtin(__builtin_amdgcn_mfma_f32_16x16x16bf16_1k)
#define MFMA16(a,b,c) __builtin_amdgcn_mfma_f32_16x16x16bf16_1k(a,b,c,0,0,0)
#else
__device__ __forceinline__ f32x4 mfma16_asm(bf16x4 a, bf16x4 b, f32x4 c) {
  asm("v_mfma_f32_16x16x16_bf16 %0, %1, %2, %0" : "+v"(c) : "v"(a), "v"(b));
  return c;
}
#define MFMA16(a,b,c) mfma16_asm(a,b,c)
#endif

#if __has_builtin(__builtin_amdgcn_exp2f)
#define EXP2F(x) __builtin_amdgcn_exp2f(x)
#else
#define EXP2F(x) exp2f(x)
#endif
#if __has_builtin(__builtin_amdgcn_rcpf)
#define RCPF(x) __builtin_amdgcn_rcpf(x)
#else
#define RCPF(x) (1.f / (x))
#endif

__device__ __forceinline__ unsigned short f2bf(float f) {
  __hip_bfloat16 h = __float2bfloat16(f);
  unsigned short u;
  __builtin_memcpy(&u, &h, 2);
  return u;
}
__device__ __forceinline__ float bf2f(unsigned short b) {
  union { unsigned u; float f; } v; v.u = ((unsigned)b) << 16; return v.f;
}
// 4x f32 -> bf16x4 via packed cvt pairs (memcpy: __hip_bfloat162 not trivially copyable)
__device__ __forceinline__ bf16x4 cvt4(f32x4 v) {
  __hip_bfloat162 a = __float22bfloat162_rn(make_float2(v[0], v[1]));
  __hip_bfloat162 b = __float22bfloat162_rn(make_float2(v[2], v[3]));
  bf16x4 r;
  __builtin_memcpy(&r, &a, 4);
  __builtin_memcpy(((char*)&r) + 4, &b, 4);
  return r;
}

// stride-128 LDS tiles: XOR elem bits 3..5 by row -> b64/b128-safe, kills the
// 256B-stride bank conflict (G4/T2).
__device__ __forceinline__ int swzK(int row, int col) {
  return row * 128 + (col ^ ((row & 7) << 3));
}

__device__ __forceinline__ bf16x8 ldfrag(const float* __restrict__ p) {
  float4 a = *(const float4*)p;
  float4 b = *(const float4*)(p + 4);
  bf16x8 fr;
  fr[0]=(short)f2bf(a.x); fr[1]=(short)f2bf(a.y); fr[2]=(short)f2bf(a.z); fr[3]=(short)f2bf(a.w);
  fr[4]=(short)f2bf(b.x); fr[5]=(short)f2bf(b.y); fr[6]=(short)f2bf(b.z); fr[7]=(short)f2bf(b.w);
  return fr;
}

__device__ __forceinline__ int pcode(int t) {       // rel-pos code
  int d = t / 49, r = t % 49;
  return d * 169 + (r / 7) * 13 + (r % 7);
}

// ---------------- prep 1: weights -> bf16 fragment-order (q: SCALE*LOG2E folded) ----------------
__global__ __launch_bounds__(512)
void prep_w(const float* __restrict__ qkv_w, const float* __restrict__ qkv_b,
            const float* __restrict__ proj_w, const float* __restrict__ proj_b,
            unsigned short* __restrict__ qpre, unsigned short* __restrict__ ppre,
            float* __restrict__ bpre)
{
  int gid = blockIdx.x * 512 + threadIdx.x;
  if (gid < 6144) {                                  // qkv: 24 row-tiles x 4 kk x 64 lanes
    int t = gid >> 8, rem = gid & 255, kk = rem >> 6, ln = rem & 63;
    int row = t * 16 + (ln & 15), col = kk * 32 + (ln >> 4) * 8;
    float sc = (row < CDIM) ? SCALE * LOG2E : 1.f;   // fold scale*log2e into Wq
    const float* s = qkv_w + (size_t)row * CDIM + col;
    unsigned short* d = qpre + (size_t)gid * 8;
#pragma unroll
    for (int e = 0; e < 8; ++e) d[e] = f2bf(s[e] * sc);
  } else if (gid < 8192) {                           // proj: 8 row-tiles
    int f2 = gid - 6144;
    int t = f2 >> 8, rem = f2 & 255, kk = rem >> 6, ln = rem & 63;
    const float* s = proj_w + (size_t)(t * 16 + (ln & 15)) * CDIM + kk * 32 + (ln >> 4) * 8;
    unsigned short* d = ppre + (size_t)f2 * 8;
#pragma unroll
    for (int e = 0; e < 8; ++e) d[e] = f2bf(s[e]);
  } else {                                           // biases (512 values)
    int i = gid - 8192;
    if (i < 384) bpre[i] = qkv_b[i] * (i < CDIM ? SCALE * LOG2E : 1.f);
    else if (i < 512) bpre[i] = proj_b[i - 384];
  }
}

// ---------------- prep 2: cmb[w][h][m][0..111] = (mask + rpb)*LOG2E (pads = -1e30) ----------------
__global__ __launch_bounds__(256)
void prep_cmb(const float* __restrict__ mask, const float* __restrict__ rpb,
              float* __restrict__ cmb, int nW)
{
  const int total = 256 * NTOK * CMBW;               // (w,h) x m x n-padded
  for (int idx = blockIdx.x * 256 + threadIdx.x; idx < total; idx += gridDim.x * 256) {
    int row = idx / CMBW, n = idx - row * CMBW;
    int wh = row / NTOK, m = row - wh * NTOK;
    int w = wh >> 2, h = wh & 3;
    float v = NEG_BIG;
    if (n < NTOK)
      v = (mask[((size_t)w * NTOK + m) * NTOK + n]
           + rpb[(pcode(m) - pcode(n) + 253) * 4 + h]) * LOG2E;
    cmb[idx] = v;
  }
}

// ---------------- main kernel ----------------
// R14 = exact R11 revert (best known: 138 us). Sequential per-unit attention,
// live set fits the 64-arch-VGPR budget at (512,4) with zero spill. R9/R12/R13
// established: >4 waves/SIMD is register-infeasible for this footprint
// ((512,6) -> ~40-arch budget; kernel needs ~90-110).
template<bool PRE>
__global__ __launch_bounds__(512, 4)
void win_attn(const float* __restrict__ x, const float* __restrict__ mask,
              const float* __restrict__ qkv_w, const float* __restrict__ qkv_b,
              const float* __restrict__ rpb, const float* __restrict__ proj_w,
              const float* __restrict__ proj_b, float* __restrict__ out, int nW,
              const float* __restrict__ cmb, const unsigned short* __restrict__ qpre,
              const unsigned short* __restrict__ ppre, const float* __restrict__ bpre)
{
  __shared__ __align__(16) unsigned short xs[(PRE ? 112 : 98) * 128]; // x; later o
  __shared__ __align__(16) unsigned short kbuf[98 * 128];             // k [tok][chan]
  __shared__ __align__(16) unsigned short vbuf[128 * 100];            // v^T [chan][tok]
  __shared__ unsigned short rpbL[PRE ? 2 : 2028];
  __shared__ short mcode[PRE ? 2 : 112];

  const int tid = threadIdx.x;
  const int lane = tid & 63;
  const int wv = tid >> 6;
  const int lm = lane & 15;
  const int lg = lane >> 4;
  const int blk = blockIdx.x;
  const int wmod = blk % nW;
  const float* __restrict__ xblk = x + (size_t)blk * (NTOK * CDIM);
  const float* __restrict__ maskw = mask + (size_t)wmod * (NTOK * NTOK);

  if constexpr (!PRE) {
    if (tid < 112) mcode[tid] = (short)(tid < NTOK ? pcode(tid) : 0);
    for (int i = tid; i < 2028; i += 512) rpbL[i] = f2bf(rpb[i]);
  }
  for (int v = tid; v < NTOK * 32; v += 512) {       // stage x -> xs (bf16, swizzled)
    int row = v >> 5, c4 = (v & 31) << 2;
    float4 f = *(const float4*)(xblk + row * CDIM + c4);
    f32x4 fv; fv[0]=f.x; fv[1]=f.y; fv[2]=f.z; fv[3]=f.w;
    *(bf16x4*)&xs[swzK(row, c4)] = cvt4(fv);
  }
  __syncthreads();

  // weight fragment accessors
  auto wq = [&](int t, int kk) -> bf16x8 {           // qkv rows (t<8: q pre-scaled)
    if constexpr (PRE) return *(const bf16x8*)&qpre[(size_t)((t * 4 + kk) * 64 + lane) * 8];
    else return ldfrag(qkv_w + (size_t)(t * 16 + lm) * CDIM + kk * 32 + lg * 8);
  };

  // ---------------- prologue: k (swapped), v (normal, transposed store), q -> regs ----------------
  {
    bf16x8 Bk[4], Bv[4];
#pragma unroll
    for (int kk = 0; kk < 4; ++kk) { Bk[kk] = wq(8 + wv, kk); Bv[kk] = wq(16 + wv, kk); }
    const float4 bk4 = *(const float4*)((PRE ? bpre : qkv_b) + CDIM + wv * 16 + lg * 4);
    const float  bv_ = (PRE ? bpre : qkv_b)[2 * CDIM + wv * 16 + lm];
    for (int mi = 0; mi < 7; ++mi) {
      int arow = mi * 16 + lm; if (arow > 97) arow = 97;
      bf16x8 A[4];
#pragma unroll
      for (int kk = 0; kk < 4; ++kk) A[kk] = *(const bf16x8*)&xs[swzK(arow, kk * 32 + lg * 8)];
      f32x4 ak = {0.f,0.f,0.f,0.f}, av = {0.f,0.f,0.f,0.f};
#pragma unroll
      for (int kk = 0; kk < 4; ++kk) {
        ak = MFMA32(Bk[kk], A[kk], ak);              // swapped: row=chan, col=token
        av = MFMA32(A[kk], Bv[kk], av);              // normal:  row=token, col=chan
      }
      int ktok = mi * 16 + lm;
      if (ktok < NTOK) {
        f32x4 t;
#pragma unroll
        for (int r = 0; r < 4; ++r) t[r] = ak[r] + ((const float*)&bk4)[r];
        *(bf16x4*)&kbuf[swzK(ktok, wv * 16 + lg * 4)] = cvt4(t);
      }
      int vtok0 = mi * 16 + lg * 4;
      if (vtok0 < 100) {                             // cols 98..99 get finite pad data
        f32x4 t;
#pragma unroll
        for (int r = 0; r < 4; ++r) t[r] = av[r] + bv_;
        *(bf16x4*)&vbuf[(size_t)(wv * 16 + lm) * 100 + vtok0] = cvt4(t);
      }
    }
  }

  const bool have1 = (wv < 6);
  const int hh0 = wv / 7, mi0 = wv % 7;
  const int mi1 = wv + 1;                            // unit u1: hh=1 (when wv<6)

  // q (swapped): lane holds q[chan][tok=lm] as B-frags for MFMA16 QK^T
  bf16x4 bq[2][2][2];                                // [j][g][ct]
#pragma unroll
  for (int j = 0; j < 2; ++j) {
    if (j == 0 || have1) {
      const int mi = j ? mi1 : mi0, hh = j ? 1 : hh0;
      int arow = mi * 16 + lm; if (arow > 97) arow = 97;
      bf16x8 Xf[4];
#pragma unroll
      for (int kk = 0; kk < 4; ++kk) Xf[kk] = *(const bf16x8*)&xs[swzK(arow, kk * 32 + lg * 8)];
#pragma unroll
      for (int g = 0; g < 2; ++g) {
        const int h = 2 * g + hh;
#pragma unroll
        for (int ct = 0; ct < 2; ++ct) {
          const int t = h * 2 + ct;                  // q row-tile
          f32x4 acc = {0.f,0.f,0.f,0.f};
#pragma unroll
          for (int kk = 0; kk < 4; ++kk) acc = MFMA32(wq(t, kk), Xf[kk], acc);
          const float4 qb4 = *(const float4*)((PRE ? bpre : qkv_b) + t * 16 + lg * 4);
          f32x4 tq;
#pragma unroll
          for (int r = 0; r < 4; ++r) {
            float vq = acc[r] + ((const float*)&qb4)[r];
            if constexpr (!PRE) vq *= SCALE * LOG2E;
            tq[r] = vq;
          }
          bq[j][g][ct] = cvt4(tq);
        }
      }
    }
  }
  __syncthreads();   // xs reads done (o overlay ok); kbuf/vbuf ready (read-only now)

  // ---------------- attention: sequential per-unit (o -> xs overlay) ----------------
#pragma unroll
  for (int g = 0; g < 2; ++g) {
#pragma unroll
    for (int j = 0; j < 2; ++j) {
      if (j == 0 || have1) {
        const int mi = j ? mi1 : mi0, hh = j ? 1 : hh0;
        const int h = 2 * g + hh, cb = h * 32;
        f32x4 s[7];
        __builtin_amdgcn_s_setprio(1);
#pragma unroll
        for (int nj = 0; nj < 7; ++nj) {             // QK^T swapped: col=m(lm), row=n
          int krow = nj * 16 + lm; if (krow > 97) krow = 97;
          bf16x4 k0 = *(const bf16x4*)&kbuf[swzK(krow, cb + lg * 4)];
          bf16x4 k1 = *(const bf16x4*)&kbuf[swzK(krow, cb + 16 + lg * 4)];
          f32x4 z = {0.f,0.f,0.f,0.f};
          z = MFMA16(k0, bq[j][g][0], z);
          s[nj] = MFMA16(k1, bq[j][g][1], z);
        }
        __builtin_amdgcn_s_setprio(0);
        const int m = mi * 16 + lm;
        const int mclamp = m > 97 ? 97 : m;
        float sum = 0.f;
        if constexpr (PRE) {
          const float* __restrict__ cp =
              cmb + ((size_t)(wmod * 4 + h) * NTOK + mclamp) * CMBW + lg * 4;
#pragma unroll
          for (int nj = 0; nj < 7; ++nj) {
            float4 cv = *(const float4*)(cp + nj * 16);
#pragma unroll
            for (int r = 0; r < 4; ++r) {
              float e = EXP2F(s[nj][r] + ((const float*)&cv)[r]);  // no-max softmax
              s[nj][r] = e; sum += e;
            }
          }
        } else {
          const int cm4 = ((int)mcode[mclamp]) * 4 + h + 1012;
          const float* __restrict__ mrow = maskw + mclamp * NTOK;
#pragma unroll
          for (int nj = 0; nj < 7; ++nj) {
            const int n0 = nj * 16 + lg * 4;
#pragma unroll
            for (int r = 0; r < 4; ++r) {
              int n = n0 + r;
              float val = NEG_BIG;
              if (n < NTOK)
                val = s[nj][r] + (mrow[n] + bf2f(rpbL[cm4 - ((int)mcode[n]) * 4])) * LOG2E;
              float e = EXP2F(val);
              s[nj][r] = e; sum += e;
            }
          }
        }
        sum += __shfl_xor(sum, 16);
        sum += __shfl_xor(sum, 32);
        const float inv = RCPF(sum);
        float invr[4];                               // inv for output row lg*4+r
#pragma unroll
        for (int r = 0; r < 4; ++r) invr[r] = __shfl(inv, lg * 4 + r);
        bf16x4 pp[7];                                // unnormalized P A-frags
#pragma unroll
        for (int nj = 0; nj < 7; ++nj) pp[nj] = cvt4(s[nj]);
        // PV: out[m][d], d = cb + dt*16 + lm; writes into xs overlay
#pragma unroll
        for (int dt = 0; dt < 2; ++dt) {
          const int d = cb + dt * 16 + lm;
          f32x4 acc = {0.f,0.f,0.f,0.f};
          __builtin_amdgcn_s_setprio(1);
#pragma unroll
          for (int nj = 0; nj < 7; ++nj) {
            const int vc = nj < 6 ? nj * 16 + lg * 4 : 96;   // clamp: P=0 there
            bf16x4 bv = *(const bf16x4*)&vbuf[(size_t)d * 100 + vc];
            acc = MFMA16(pp[nj], bv, acc);
          }
          __builtin_amdgcn_s_setprio(0);
#pragma unroll
          for (int r = 0; r < 4; ++r) {
            int m2 = mi * 16 + lg * 4 + r;
            if (PRE || m2 < NTOK) xs[swzK(m2, d)] = f2bf(acc[r] * invr[r]);
          }
        }
      }
    }
  }
  __syncthreads();   // o complete

  // ---------------- GEMM3 (swapped): out = o @ Wp^T, float4 stores ----------------
  {
    bf16x8 Bp[4];
#pragma unroll
    for (int kk = 0; kk < 4; ++kk) {
      if constexpr (PRE) Bp[kk] = *(const bf16x8*)&ppre[(size_t)((wv * 4 + kk) * 64 + lane) * 8];
      else Bp[kk] = ldfrag(proj_w + (size_t)(wv * 16 + lm) * CDIM + kk * 32 + lg * 8);
    }
    const float4 pb4 = *(const float4*)((PRE ? bpre + 384 : proj_b) + wv * 16 + lg * 4);
    float* __restrict__ outb = out + (size_t)blk * (NTOK * CDIM);
    for (int mi = 0; mi < 7; ++mi) {
      int orow = mi * 16 + lm;
      if (!PRE && orow > 97) orow = 97;
      f32x4 acc = {0.f,0.f,0.f,0.f};
#pragma unroll
      for (int kk = 0; kk < 4; ++kk) {
        bf16x8 Bo = *(const bf16x8*)&xs[swzK(orow, kk * 32 + lg * 8)];
        acc = MFMA32(Bp[kk], Bo, acc);               // row=out-chan, col=token
      }
      int tok = mi * 16 + lm;
      if (tok < NTOK) {
        float4 o4;
        o4.x = acc[0] + pb4.x; o4.y = acc[1] + pb4.y;
        o4.z = acc[2] + pb4.z; o4.w = acc[3] + pb4.w;
        *(float4*)(outb + (size_t)tok * CDIM + wv * 16 + lg * 4) = o4;
      }
    }
  }
}

extern "C" void kernel_launch(void* const* d_in, const int* in_sizes, int n_in,
                              void* d_out, int out_size, void* d_ws, size_t ws_size,
                              hipStream_t stream) {
  const float* x      = (const float*)d_in[0];
  const float* mask   = (const float*)d_in[1];
  const float* qkv_w  = (const float*)d_in[2];
  const float* qkv_b  = (const float*)d_in[3];
  const float* rpb    = (const float*)d_in[4];
  const float* proj_w = (const float*)d_in[5];
  const float* proj_b = (const float*)d_in[6];
  int B  = in_sizes[0] / (NTOK * CDIM);
  int nW = in_sizes[1] / (NTOK * NTOK);

  const size_t CMB_B  = (size_t)256 * NTOK * CMBW * 4;  // 11,239,424
  const size_t QPRE_B = 24 * 4 * 64 * 8 * 2;            // 98,304
  const size_t PPRE_B = 8 * 4 * 64 * 8 * 2;             // 32,768
  const size_t BIAS_B = 512 * 4;
  const size_t need = CMB_B + QPRE_B + PPRE_B + BIAS_B;

  if (ws_size >= need) {
    float* cmb = (float*)d_ws;
    unsigned short* qpre = (unsigned short*)((char*)d_ws + CMB_B);
    unsigned short* ppre = (unsigned short*)((char*)d_ws + CMB_B + QPRE_B);
    float* bpre = (float*)((char*)d_ws + CMB_B + QPRE_B + PPRE_B);
    hipLaunchKernelGGL(prep_w, dim3(17), dim3(512), 0, stream,
                       qkv_w, qkv_b, proj_w, proj_b, qpre, ppre, bpre);
    hipLaunchKernelGGL(prep_cmb, dim3(1024), dim3(256), 0, stream, mask, rpb, cmb, nW);
    hipLaunchKernelGGL(win_attn<true>, dim3(B), dim3(512), 0, stream,
                       x, mask, qkv_w, qkv_b, rpb, proj_w, proj_b, (float*)d_out, nW,
                       cmb, qpre, ppre, bpre);
  } else {
    hipLaunchKernelGGL(win_attn<false>, dim3(B), dim3(512), 0, stream,
                       x, mask, qkv_w, qkv_b, rpb, proj_w, proj_b, (float*)d_out, nW,
                       (const float*)nullptr, (const unsigned short*)nullptr,
                       (const unsigned short*)nullptr, (const float*)nullptr);
  }
}

// Round 15
// 127.005 us; speedup vs baseline: 1.4747x; 1.0864x over previous
//
#include <hip/hip_runtime.h>
#include <hip/hip_bf16.h>

#define NTOK 98
#define CDIM 128
#define SCALE 0.17677669529663687f
#define LOG2E 1.4426950408889634f
#define NEG_BIG -1e30f
#define CMBW 112   // cmb row width: covers full fragment n-range 0..111

typedef short bf16x8 __attribute__((ext_vector_type(8)));
typedef short bf16x4 __attribute__((ext_vector_type(4)));
typedef float f32x4 __attribute__((ext_vector_type(4)));

#define MFMA32(a,b,c) __builtin_amdgcn_mfma_f32_16x16x32_bf16(a,b,c,0,0,0)

#if __has_builtin(__builtin_amdgcn_mfma_f32_16x16x16_bf16)
#define MFMA16(a,b,c) __builtin_amdgcn_mfma_f32_16x16x16_bf16(a,b,c,0,0,0)
#elif __has_builtin(__builtin_amdgcn_mfma_f32_16x16x16bf16_1k)
#define MFMA16(a,b,c) __builtin_amdgcn_mfma_f32_16x16x16bf16_1k(a,b,c,0,0,0)
#else
__device__ __forceinline__ f32x4 mfma16_asm(bf16x4 a, bf16x4 b, f32x4 c) {
  asm("v_mfma_f32_16x16x16_bf16 %0, %1, %2, %0" : "+v"(c) : "v"(a), "v"(b));
  return c;
}
#define MFMA16(a,b,c) mfma16_asm(a,b,c)
#endif

#if __has_builtin(__builtin_amdgcn_exp2f)
#define EXP2F(x) __builtin_amdgcn_exp2f(x)
#else
#define EXP2F(x) exp2f(x)
#endif
#if __has_builtin(__builtin_amdgcn_rcpf)
#define RCPF(x) __builtin_amdgcn_rcpf(x)
#else
#define RCPF(x) (1.f / (x))
#endif

__device__ __forceinline__ unsigned short f2bf(float f) {
  __hip_bfloat16 h = __float2bfloat16(f);
  unsigned short u;
  __builtin_memcpy(&u, &h, 2);
  return u;
}
__device__ __forceinline__ float bf2f(unsigned short b) {
  union { unsigned u; float f; } v; v.u = ((unsigned)b) << 16; return v.f;
}
// 4x f32 -> bf16x4 via packed cvt pairs (memcpy: __hip_bfloat162 not trivially copyable)
__device__ __forceinline__ bf16x4 cvt4(f32x4 v) {
  __hip_bfloat162 a = __float22bfloat162_rn(make_float2(v[0], v[1]));
  __hip_bfloat162 b = __float22bfloat162_rn(make_float2(v[2], v[3]));
  bf16x4 r;
  __builtin_memcpy(&r, &a, 4);
  __builtin_memcpy(((char*)&r) + 4, &b, 4);
  return r;
}

// stride-128 LDS tiles: XOR elem bits 3..5 by row -> b64/b128-safe, kills the
// 256B-stride bank conflict (G4/T2).
__device__ __forceinline__ int swzK(int row, int col) {
  return row * 128 + (col ^ ((row & 7) << 3));
}

__device__ __forceinline__ bf16x8 ldfrag(const float* __restrict__ p) {
  float4 a = *(const float4*)p;
  float4 b = *(const float4*)(p + 4);
  bf16x8 fr;
  fr[0]=(short)f2bf(a.x); fr[1]=(short)f2bf(a.y); fr[2]=(short)f2bf(a.z); fr[3]=(short)f2bf(a.w);
  fr[4]=(short)f2bf(b.x); fr[5]=(short)f2bf(b.y); fr[6]=(short)f2bf(b.z); fr[7]=(short)f2bf(b.w);
  return fr;
}

__device__ __forceinline__ int pcode(int t) {       // rel-pos code
  int d = t / 49, r = t % 49;
  return d * 169 + (r / 7) * 13 + (r % 7);
}

// ---------------- prep 1: weights -> bf16 fragment-order (q: SCALE*LOG2E folded) ----------------
__global__ __launch_bounds__(512)
void prep_w(const float* __restrict__ qkv_w, const float* __restrict__ qkv_b,
            const float* __restrict__ proj_w, const float* __restrict__ proj_b,
            unsigned short* __restrict__ qpre, unsigned short* __restrict__ ppre,
            float* __restrict__ bpre)
{
  int gid = blockIdx.x * 512 + threadIdx.x;
  if (gid < 6144) {                                  // qkv: 24 row-tiles x 4 kk x 64 lanes
    int t = gid >> 8, rem = gid & 255, kk = rem >> 6, ln = rem & 63;
    int row = t * 16 + (ln & 15), col = kk * 32 + (ln >> 4) * 8;
    float sc = (row < CDIM) ? SCALE * LOG2E : 1.f;   // fold scale*log2e into Wq
    const float* s = qkv_w + (size_t)row * CDIM + col;
    unsigned short* d = qpre + (size_t)gid * 8;
#pragma unroll
    for (int e = 0; e < 8; ++e) d[e] = f2bf(s[e] * sc);
  } else if (gid < 8192) {                           // proj: 8 row-tiles
    int f2 = gid - 6144;
    int t = f2 >> 8, rem = f2 & 255, kk = rem >> 6, ln = rem & 63;
    const float* s = proj_w + (size_t)(t * 16 + (ln & 15)) * CDIM + kk * 32 + (ln >> 4) * 8;
    unsigned short* d = ppre + (size_t)f2 * 8;
#pragma unroll
    for (int e = 0; e < 8; ++e) d[e] = f2bf(s[e]);
  } else {                                           // biases (512 values)
    int i = gid - 8192;
    if (i < 384) bpre[i] = qkv_b[i] * (i < CDIM ? SCALE * LOG2E : 1.f);
    else if (i < 512) bpre[i] = proj_b[i - 384];
  }
}

// ---------------- prep 2: cmb[w][h][m][0..111] = (mask + rpb)*LOG2E (pads = -1e30) ----------------
__global__ __launch_bounds__(256)
void prep_cmb(const float* __restrict__ mask, const float* __restrict__ rpb,
              float* __restrict__ cmb, int nW)
{
  const int total = 256 * NTOK * CMBW;               // (w,h) x m x n-padded
  for (int idx = blockIdx.x * 256 + threadIdx.x; idx < total; idx += gridDim.x * 256) {
    int row = idx / CMBW, n = idx - row * CMBW;
    int wh = row / NTOK, m = row - wh * NTOK;
    int w = wh >> 2, h = wh & 3;
    float v = NEG_BIG;
    if (n < NTOK)
      v = (mask[((size_t)w * NTOK + m) * NTOK + n]
           + rpb[(pcode(m) - pcode(n) + 253) * 4 + h]) * LOG2E;
    cmb[idx] = v;
  }
}

// ---------------- main kernel ----------------
// R15: 1024-thread blocks (16 waves), SAME 79 KB LDS -> still 2 blocks/CU but
// 32 waves/CU = 8 waves/EU (was 16/CU). The 8-waves/EU VGPR budget is 64 --
// exactly what R11/R14 proved this kernel fits with zero spill (unlike R12/R13's
// 3-block path, whose 6-waves/EU budget of ~40 forced spill). Per-wave serial
// work HALVES: prologue = 1 k-or-v tile (was k+v), attention = 2 units (was 4),
// no have1 imbalance (14 units over 16 waves, one each); bq 16->8 regs.
template<bool PRE>
__global__ __launch_bounds__(1024, 8)
void win_attn(const float* __restrict__ x, const float* __restrict__ mask,
              const float* __restrict__ qkv_w, const float* __restrict__ qkv_b,
              const float* __restrict__ rpb, const float* __restrict__ proj_w,
              const float* __restrict__ proj_b, float* __restrict__ out, int nW,
              const float* __restrict__ cmb, const unsigned short* __restrict__ qpre,
              const unsigned short* __restrict__ ppre, const float* __restrict__ bpre)
{
  __shared__ __align__(16) unsigned short xs[(PRE ? 112 : 98) * 128]; // x; later o
  __shared__ __align__(16) unsigned short kbuf[98 * 128];             // k [tok][chan] (swapped)
  __shared__ __align__(16) unsigned short vbuf[128 * 100];            // v^T [chan][tok]
  __shared__ unsigned short rpbL[PRE ? 2 : 2028];
  __shared__ short mcode[PRE ? 2 : 112];

  const int tid = threadIdx.x;
  const int lane = tid & 63;
  const int wv = tid >> 6;                           // wave 0..15
  const int lm = lane & 15;
  const int lg = lane >> 4;
  const int blk = blockIdx.x;
  const int wmod = blk % nW;
  const float* __restrict__ xblk = x + (size_t)blk * (NTOK * CDIM);
  const float* __restrict__ maskw = mask + (size_t)wmod * (NTOK * NTOK);
  const float* __restrict__ bias = PRE ? bpre : qkv_b;

  if constexpr (!PRE) {
    if (tid < 112) mcode[tid] = (short)(tid < NTOK ? pcode(tid) : 0);
    for (int i = tid; i < 2028; i += 1024) rpbL[i] = f2bf(rpb[i]);
  }
  for (int v = tid; v < NTOK * 32; v += 1024) {      // stage x -> xs (bf16, swizzled)
    int row = v >> 5, c4 = (v & 31) << 2;
    float4 f = *(const float4*)(xblk + row * CDIM + c4);
    f32x4 fv; fv[0]=f.x; fv[1]=f.y; fv[2]=f.z; fv[3]=f.w;
    *(bf16x4*)&xs[swzK(row, c4)] = cvt4(fv);
  }
  __syncthreads();

  // weight fragment accessors
  auto wq = [&](int t, int kk) -> bf16x8 {           // qkv rows (t<8: q pre-scaled)
    if constexpr (PRE) return *(const bf16x8*)&qpre[(size_t)((t * 4 + kk) * 64 + lane) * 8];
    else return ldfrag(qkv_w + (size_t)(t * 16 + lm) * CDIM + kk * 32 + lg * 8);
  };

  // ---------------- prologue: waves 0-7 -> k tile wv (swapped); 8-15 -> v tile wv-8 ----------------
  if (wv < 8) {
    bf16x8 Bk[4];
#pragma unroll
    for (int kk = 0; kk < 4; ++kk) Bk[kk] = wq(8 + wv, kk);
    const float4 bk4 = *(const float4*)(bias + CDIM + wv * 16 + lg * 4);
    for (int mi = 0; mi < 7; ++mi) {
      int arow = mi * 16 + lm; if (arow > 97) arow = 97;
      bf16x8 A[4];
#pragma unroll
      for (int kk = 0; kk < 4; ++kk) A[kk] = *(const bf16x8*)&xs[swzK(arow, kk * 32 + lg * 8)];
      f32x4 ak = {0.f,0.f,0.f,0.f};
#pragma unroll
      for (int kk = 0; kk < 4; ++kk) ak = MFMA32(Bk[kk], A[kk], ak);  // swapped: row=chan, col=tok
      int ktok = mi * 16 + lm;
      if (ktok < NTOK) {
        f32x4 t;
#pragma unroll
        for (int r = 0; r < 4; ++r) t[r] = ak[r] + ((const float*)&bk4)[r];
        *(bf16x4*)&kbuf[swzK(ktok, wv * 16 + lg * 4)] = cvt4(t);
      }
    }
  } else {
    const int vt = wv - 8;
    bf16x8 Bv[4];
#pragma unroll
    for (int kk = 0; kk < 4; ++kk) Bv[kk] = wq(16 + vt, kk);
    const float bv_ = bias[2 * CDIM + vt * 16 + lm];
    for (int mi = 0; mi < 7; ++mi) {
      int arow = mi * 16 + lm; if (arow > 97) arow = 97;
      bf16x8 A[4];
#pragma unroll
      for (int kk = 0; kk < 4; ++kk) A[kk] = *(const bf16x8*)&xs[swzK(arow, kk * 32 + lg * 8)];
      f32x4 av = {0.f,0.f,0.f,0.f};
#pragma unroll
      for (int kk = 0; kk < 4; ++kk) av = MFMA32(A[kk], Bv[kk], av);  // normal: row=tok, col=chan
      int vtok0 = mi * 16 + lg * 4;
      if (vtok0 < 100) {                             // cols 98..99 get finite pad data
        f32x4 t;
#pragma unroll
        for (int r = 0; r < 4; ++r) t[r] = av[r] + bv_;
        *(bf16x4*)&vbuf[(size_t)(vt * 16 + lm) * 100 + vtok0] = cvt4(t);
      }
    }
  }

  // ---- one attention unit per wave: unit wv = (hh, mi), hh = wv/7, mi = wv%7 ----
  const bool active = (wv < 14);
  const int hh = wv / 7, mi = wv % 7;

  // q (swapped): lane holds q[chan][tok=lm] as B-frags for MFMA16 QK^T
  bf16x4 bq[2][2];                                   // [g][ct]
  if (active) {
    int arow = mi * 16 + lm; if (arow > 97) arow = 97;
    bf16x8 Xf[4];
#pragma unroll
    for (int kk = 0; kk < 4; ++kk) Xf[kk] = *(const bf16x8*)&xs[swzK(arow, kk * 32 + lg * 8)];
#pragma unroll
    for (int g = 0; g < 2; ++g) {
      const int h = 2 * g + hh;
#pragma unroll
      for (int ct = 0; ct < 2; ++ct) {
        const int t = h * 2 + ct;                    // q row-tile
        f32x4 acc = {0.f,0.f,0.f,0.f};
#pragma unroll
        for (int kk = 0; kk < 4; ++kk) acc = MFMA32(wq(t, kk), Xf[kk], acc);
        const float4 qb4 = *(const float4*)(bias + t * 16 + lg * 4);
        f32x4 tq;
#pragma unroll
        for (int r = 0; r < 4; ++r) {
          float vq = acc[r] + ((const float*)&qb4)[r];
          if constexpr (!PRE) vq *= SCALE * LOG2E;
          tq[r] = vq;
        }
        bq[g][ct] = cvt4(tq);
      }
    }
  }
  __syncthreads();   // xs reads done (o overlay ok); kbuf/vbuf ready (read-only now)

  // ---------------- attention: 2 units per wave (g=0,1), o -> xs overlay ----------------
#pragma unroll
  for (int g = 0; g < 2; ++g) {
    if (active) {
      const int h = 2 * g + hh, cb = h * 32;
      f32x4 s[7];
      __builtin_amdgcn_s_setprio(1);
#pragma unroll
      for (int nj = 0; nj < 7; ++nj) {               // QK^T swapped: col=m(lm), row=n
        int krow = nj * 16 + lm; if (krow > 97) krow = 97;
        bf16x4 k0 = *(const bf16x4*)&kbuf[swzK(krow, cb + lg * 4)];
        bf16x4 k1 = *(const bf16x4*)&kbuf[swzK(krow, cb + 16 + lg * 4)];
        f32x4 z = {0.f,0.f,0.f,0.f};
        z = MFMA16(k0, bq[g][0], z);
        s[nj] = MFMA16(k1, bq[g][1], z);
      }
      __builtin_amdgcn_s_setprio(0);
      const int m = mi * 16 + lm;
      const int mclamp = m > 97 ? 97 : m;
      float sum = 0.f;
      if constexpr (PRE) {
        const float* __restrict__ cp =
            cmb + ((size_t)(wmod * 4 + h) * NTOK + mclamp) * CMBW + lg * 4;
#pragma unroll
        for (int nj = 0; nj < 7; ++nj) {
          float4 cv = *(const float4*)(cp + nj * 16);
#pragma unroll
          for (int r = 0; r < 4; ++r) {
            float e = EXP2F(s[nj][r] + ((const float*)&cv)[r]);  // no-max softmax
            s[nj][r] = e; sum += e;
          }
        }
      } else {
        const int cm4 = ((int)mcode[mclamp]) * 4 + h + 1012;
        const float* __restrict__ mrow = maskw + mclamp * NTOK;
#pragma unroll
        for (int nj = 0; nj < 7; ++nj) {
          const int n0 = nj * 16 + lg * 4;
#pragma unroll
          for (int r = 0; r < 4; ++r) {
            int n = n0 + r;
            float val = NEG_BIG;
            if (n < NTOK)
              val = s[nj][r] + (mrow[n] + bf2f(rpbL[cm4 - ((int)mcode[n]) * 4])) * LOG2E;
            float e = EXP2F(val);
            s[nj][r] = e; sum += e;
          }
        }
      }
      sum += __shfl_xor(sum, 16);
      sum += __shfl_xor(sum, 32);
      const float inv = RCPF(sum);
      float invr[4];                                 // inv for output row lg*4+r
#pragma unroll
      for (int r = 0; r < 4; ++r) invr[r] = __shfl(inv, lg * 4 + r);
      bf16x4 pp[7];                                  // unnormalized P A-frags
#pragma unroll
      for (int nj = 0; nj < 7; ++nj) pp[nj] = cvt4(s[nj]);
      // PV: out[m][d], d = cb + dt*16 + lm; writes into xs overlay
#pragma unroll
      for (int dt = 0; dt < 2; ++dt) {
        const int d = cb + dt * 16 + lm;
        f32x4 acc = {0.f,0.f,0.f,0.f};
        __builtin_amdgcn_s_setprio(1);
#pragma unroll
        for (int nj = 0; nj < 7; ++nj) {
          const int vc = nj < 6 ? nj * 16 + lg * 4 : 96;     // clamp: P=0 there
          bf16x4 bv = *(const bf16x4*)&vbuf[(size_t)d * 100 + vc];
          acc = MFMA16(pp[nj], bv, acc);
        }
        __builtin_amdgcn_s_setprio(0);
#pragma unroll
        for (int r = 0; r < 4; ++r) {
          int m2 = mi * 16 + lg * 4 + r;
          if (PRE || m2 < NTOK) xs[swzK(m2, d)] = f2bf(acc[r] * invr[r]);
        }
      }
    }
  }
  __syncthreads();   // o complete

  // ---------------- GEMM3 (swapped): out = o @ Wp^T, float4 stores ----------------
  // 8 col-tiles x 7 mi over 16 waves: wave wv -> tile (wv&7), mi in (wv<8 ? 0..3 : 4..6)
  {
    const int ct8 = wv & 7;
    bf16x8 Bp[4];
#pragma unroll
    for (int kk = 0; kk < 4; ++kk) {
      if constexpr (PRE) Bp[kk] = *(const bf16x8*)&ppre[(size_t)((ct8 * 4 + kk) * 64 + lane) * 8];
      else Bp[kk] = ldfrag(proj_w + (size_t)(ct8 * 16 + lm) * CDIM + kk * 32 + lg * 8);
    }
    const float4 pb4 = *(const float4*)((PRE ? bpre + 384 : proj_b) + ct8 * 16 + lg * 4);
    float* __restrict__ outb = out + (size_t)blk * (NTOK * CDIM);
    const int mlo = wv < 8 ? 0 : 4, mhi = wv < 8 ? 4 : 7;
    for (int mi2 = mlo; mi2 < mhi; ++mi2) {
      int orow = mi2 * 16 + lm;
      if (!PRE && orow > 97) orow = 97;
      f32x4 acc = {0.f,0.f,0.f,0.f};
#pragma unroll
      for (int kk = 0; kk < 4; ++kk) {
        bf16x8 Bo = *(const bf16x8*)&xs[swzK(orow, kk * 32 + lg * 8)];
        acc = MFMA32(Bp[kk], Bo, acc);               // row=out-chan, col=token
      }
      int tok = mi2 * 16 + lm;
      if (tok < NTOK) {
        float4 o4;
        o4.x = acc[0] + pb4.x; o4.y = acc[1] + pb4.y;
        o4.z = acc[2] + pb4.z; o4.w = acc[3] + pb4.w;
        *(float4*)(outb + (size_t)tok * CDIM + ct8 * 16 + lg * 4) = o4;
      }
    }
  }
}

extern "C" void kernel_launch(void* const* d_in, const int* in_sizes, int n_in,
                              void* d_out, int out_size, void* d_ws, size_t ws_size,
                              hipStream_t stream) {
  const float* x      = (const float*)d_in[0];
  const float* mask   = (const float*)d_in[1];
  const float* qkv_w  = (const float*)d_in[2];
  const float* qkv_b  = (const float*)d_in[3];
  const float* rpb    = (const float*)d_in[4];
  const float* proj_w = (const float*)d_in[5];
  const float* proj_b = (const float*)d_in[6];
  int B  = in_sizes[0] / (NTOK * CDIM);
  int nW = in_sizes[1] / (NTOK * NTOK);

  const size_t CMB_B  = (size_t)256 * NTOK * CMBW * 4;  // 11,239,424
  const size_t QPRE_B = 24 * 4 * 64 * 8 * 2;            // 98,304
  const size_t PPRE_B = 8 * 4 * 64 * 8 * 2;             // 32,768
  const size_t BIAS_B = 512 * 4;
  const size_t need = CMB_B + QPRE_B + PPRE_B + BIAS_B;

  if (ws_size >= need) {
    float* cmb = (float*)d_ws;
    unsigned short* qpre = (unsigned short*)((char*)d_ws + CMB_B);
    unsigned short* ppre = (unsigned short*)((char*)d_ws + CMB_B + QPRE_B);
    float* bpre = (float*)((char*)d_ws + CMB_B + QPRE_B + PPRE_B);
    hipLaunchKernelGGL(prep_w, dim3(17), dim3(512), 0, stream,
                       qkv_w, qkv_b, proj_w, proj_b, qpre, ppre, bpre);
    hipLaunchKernelGGL(prep_cmb, dim3(1024), dim3(256), 0, stream, mask, rpb, cmb, nW);
    hipLaunchKernelGGL(win_attn<true>, dim3(B), dim3(1024), 0, stream,
                       x, mask, qkv_w, qkv_b, rpb, proj_w, proj_b, (float*)d_out, nW,
                       cmb, qpre, ppre, bpre);
  } else {
    hipLaunchKernelGGL(win_attn<false>, dim3(B), dim3(1024), 0, stream,
                       x, mask, qkv_w, qkv_b, rpb, proj_w, proj_b, (float*)d_out, nW,
                       (const float*)nullptr, (const unsigned short*)nullptr,
                       (const unsigned short*)nullptr, (const float*)nullptr);
  }
}

// Round 16
// 126.591 us; speedup vs baseline: 1.4795x; 1.0033x over previous
//
#include <hip/hip_runtime.h>
#include <hip/hip_bf16.h>

#define NTOK 98
#define CDIM 128
#define SCALE 0.17677669529663687f
#define LOG2E 1.4426950408889634f
#define NEG_BIG -1e30f
#define CMBW 112   // cmb row width: covers full fragment n-range 0..111

typedef short bf16x8 __attribute__((ext_vector_type(8)));
typedef short bf16x4 __attribute__((ext_vector_type(4)));
typedef float f32x4 __attribute__((ext_vector_type(4)));

#define MFMA32(a,b,c) __builtin_amdgcn_mfma_f32_16x16x32_bf16(a,b,c,0,0,0)

#if __has_builtin(__builtin_amdgcn_mfma_f32_16x16x16_bf16)
#define MFMA16(a,b,c) __builtin_amdgcn_mfma_f32_16x16x16_bf16(a,b,c,0,0,0)
#elif __has_builtin(__builtin_amdgcn_mfma_f32_16x16x16bf16_1k)
#define MFMA16(a,b,c) __builtin_amdgcn_mfma_f32_16x16x16bf16_1k(a,b,c,0,0,0)
#else
__device__ __forceinline__ f32x4 mfma16_asm(bf16x4 a, bf16x4 b, f32x4 c) {
  asm("v_mfma_f32_16x16x16_bf16 %0, %1, %2, %0" : "+v"(c) : "v"(a), "v"(b));
  return c;
}
#define MFMA16(a,b,c) mfma16_asm(a,b,c)
#endif

#if __has_builtin(__builtin_amdgcn_exp2f)
#define EXP2F(x) __builtin_amdgcn_exp2f(x)
#else
#define EXP2F(x) exp2f(x)
#endif
#if __has_builtin(__builtin_amdgcn_rcpf)
#define RCPF(x) __builtin_amdgcn_rcpf(x)
#else
#define RCPF(x) (1.f / (x))
#endif

__device__ __forceinline__ unsigned short f2bf(float f) {
  __hip_bfloat16 h = __float2bfloat16(f);
  unsigned short u;
  __builtin_memcpy(&u, &h, 2);
  return u;
}
__device__ __forceinline__ float bf2f(unsigned short b) {
  union { unsigned u; float f; } v; v.u = ((unsigned)b) << 16; return v.f;
}
// 4x f32 -> bf16x4 via packed cvt pairs (memcpy: __hip_bfloat162 not trivially copyable)
__device__ __forceinline__ bf16x4 cvt4(f32x4 v) {
  __hip_bfloat162 a = __float22bfloat162_rn(make_float2(v[0], v[1]));
  __hip_bfloat162 b = __float22bfloat162_rn(make_float2(v[2], v[3]));
  bf16x4 r;
  __builtin_memcpy(&r, &a, 4);
  __builtin_memcpy(((char*)&r) + 4, &b, 4);
  return r;
}

// stride-128 LDS tiles: XOR elem bits 3..5 by row -> b64/b128-safe, kills the
// 256B-stride bank conflict (G4/T2).
__device__ __forceinline__ int swzK(int row, int col) {
  return row * 128 + (col ^ ((row & 7) << 3));
}

__device__ __forceinline__ bf16x8 ldfrag(const float* __restrict__ p) {
  float4 a = *(const float4*)p;
  float4 b = *(const float4*)(p + 4);
  bf16x8 fr;
  fr[0]=(short)f2bf(a.x); fr[1]=(short)f2bf(a.y); fr[2]=(short)f2bf(a.z); fr[3]=(short)f2bf(a.w);
  fr[4]=(short)f2bf(b.x); fr[5]=(short)f2bf(b.y); fr[6]=(short)f2bf(b.z); fr[7]=(short)f2bf(b.w);
  return fr;
}

__device__ __forceinline__ int pcode(int t) {       // rel-pos code
  int d = t / 49, r = t % 49;
  return d * 169 + (r / 7) * 13 + (r % 7);
}

// ---------------- prep 1: weights -> bf16 fragment-order (q: SCALE*LOG2E folded) ----------------
__global__ __launch_bounds__(512)
void prep_w(const float* __restrict__ qkv_w, const float* __restrict__ qkv_b,
            const float* __restrict__ proj_w, const float* __restrict__ proj_b,
            unsigned short* __restrict__ qpre, unsigned short* __restrict__ ppre,
            float* __restrict__ bpre)
{
  int gid = blockIdx.x * 512 + threadIdx.x;
  if (gid < 6144) {                                  // qkv: 24 row-tiles x 4 kk x 64 lanes
    int t = gid >> 8, rem = gid & 255, kk = rem >> 6, ln = rem & 63;
    int row = t * 16 + (ln & 15), col = kk * 32 + (ln >> 4) * 8;
    float sc = (row < CDIM) ? SCALE * LOG2E : 1.f;   // fold scale*log2e into Wq
    const float* s = qkv_w + (size_t)row * CDIM + col;
    unsigned short* d = qpre + (size_t)gid * 8;
#pragma unroll
    for (int e = 0; e < 8; ++e) d[e] = f2bf(s[e] * sc);
  } else if (gid < 8192) {                           // proj: 8 row-tiles
    int f2 = gid - 6144;
    int t = f2 >> 8, rem = f2 & 255, kk = rem >> 6, ln = rem & 63;
    const float* s = proj_w + (size_t)(t * 16 + (ln & 15)) * CDIM + kk * 32 + (ln >> 4) * 8;
    unsigned short* d = ppre + (size_t)f2 * 8;
#pragma unroll
    for (int e = 0; e < 8; ++e) d[e] = f2bf(s[e]);
  } else {                                           // biases (512 values)
    int i = gid - 8192;
    if (i < 384) bpre[i] = qkv_b[i] * (i < CDIM ? SCALE * LOG2E : 1.f);
    else if (i < 512) bpre[i] = proj_b[i - 384];
  }
}

// ---------------- prep 2: cmb[w][h][m][0..111] = (mask + rpb)*LOG2E (pads = -1e30) ----------------
__global__ __launch_bounds__(256)
void prep_cmb(const float* __restrict__ mask, const float* __restrict__ rpb,
              float* __restrict__ cmb, int nW)
{
  const int total = 256 * NTOK * CMBW;               // (w,h) x m x n-padded
  for (int idx = blockIdx.x * 256 + threadIdx.x; idx < total; idx += gridDim.x * 256) {
    int row = idx / CMBW, n = idx - row * CMBW;
    int wh = row / NTOK, m = row - wh * NTOK;
    int w = wh >> 2, h = wh & 3;
    float v = NEG_BIG;
    if (n < NTOK)
      v = (mask[((size_t)w * NTOK + m) * NTOK + n]
           + rpb[(pcode(m) - pcode(n) + 253) * 4 + h]) * LOG2E;
    cmb[idx] = v;
  }
}

// ---------------- main kernel ----------------
// R16 = R15 (1024-thread, 81% occupancy) + softmax memory-level parallelism:
// (1) preload all 7 cmb float4s before the exp loop (R15's VGPR=32 meant the
// compiler consumed each load immediately -> 7 serial L2 latencies inside a
// barrier-aligned phase); (2) 4-way softmax sum split (28-add serial chain ->
// 7); (3) preload PV's 7 vbuf B-frags ahead of the MFMA chain.
template<bool PRE>
__global__ __launch_bounds__(1024, 8)
void win_attn(const float* __restrict__ x, const float* __restrict__ mask,
              const float* __restrict__ qkv_w, const float* __restrict__ qkv_b,
              const float* __restrict__ rpb, const float* __restrict__ proj_w,
              const float* __restrict__ proj_b, float* __restrict__ out, int nW,
              const float* __restrict__ cmb, const unsigned short* __restrict__ qpre,
              const unsigned short* __restrict__ ppre, const float* __restrict__ bpre)
{
  __shared__ __align__(16) unsigned short xs[(PRE ? 112 : 98) * 128]; // x; later o
  __shared__ __align__(16) unsigned short kbuf[98 * 128];             // k [tok][chan] (swapped)
  __shared__ __align__(16) unsigned short vbuf[128 * 100];            // v^T [chan][tok]
  __shared__ unsigned short rpbL[PRE ? 2 : 2028];
  __shared__ short mcode[PRE ? 2 : 112];

  const int tid = threadIdx.x;
  const int lane = tid & 63;
  const int wv = tid >> 6;                           // wave 0..15
  const int lm = lane & 15;
  const int lg = lane >> 4;
  const int blk = blockIdx.x;
  const int wmod = blk % nW;
  const float* __restrict__ xblk = x + (size_t)blk * (NTOK * CDIM);
  const float* __restrict__ maskw = mask + (size_t)wmod * (NTOK * NTOK);
  const float* __restrict__ bias = PRE ? bpre : qkv_b;

  if constexpr (!PRE) {
    if (tid < 112) mcode[tid] = (short)(tid < NTOK ? pcode(tid) : 0);
    for (int i = tid; i < 2028; i += 1024) rpbL[i] = f2bf(rpb[i]);
  }
  for (int v = tid; v < NTOK * 32; v += 1024) {      // stage x -> xs (bf16, swizzled)
    int row = v >> 5, c4 = (v & 31) << 2;
    float4 f = *(const float4*)(xblk + row * CDIM + c4);
    f32x4 fv; fv[0]=f.x; fv[1]=f.y; fv[2]=f.z; fv[3]=f.w;
    *(bf16x4*)&xs[swzK(row, c4)] = cvt4(fv);
  }
  __syncthreads();

  // weight fragment accessors
  auto wq = [&](int t, int kk) -> bf16x8 {           // qkv rows (t<8: q pre-scaled)
    if constexpr (PRE) return *(const bf16x8*)&qpre[(size_t)((t * 4 + kk) * 64 + lane) * 8];
    else return ldfrag(qkv_w + (size_t)(t * 16 + lm) * CDIM + kk * 32 + lg * 8);
  };

  // ---------------- prologue: waves 0-7 -> k tile wv (swapped); 8-15 -> v tile wv-8 ----------------
  if (wv < 8) {
    bf16x8 Bk[4];
#pragma unroll
    for (int kk = 0; kk < 4; ++kk) Bk[kk] = wq(8 + wv, kk);
    const float4 bk4 = *(const float4*)(bias + CDIM + wv * 16 + lg * 4);
    for (int mi = 0; mi < 7; ++mi) {
      int arow = mi * 16 + lm; if (arow > 97) arow = 97;
      bf16x8 A[4];
#pragma unroll
      for (int kk = 0; kk < 4; ++kk) A[kk] = *(const bf16x8*)&xs[swzK(arow, kk * 32 + lg * 8)];
      f32x4 ak = {0.f,0.f,0.f,0.f};
#pragma unroll
      for (int kk = 0; kk < 4; ++kk) ak = MFMA32(Bk[kk], A[kk], ak);  // swapped: row=chan, col=tok
      int ktok = mi * 16 + lm;
      if (ktok < NTOK) {
        f32x4 t;
#pragma unroll
        for (int r = 0; r < 4; ++r) t[r] = ak[r] + ((const float*)&bk4)[r];
        *(bf16x4*)&kbuf[swzK(ktok, wv * 16 + lg * 4)] = cvt4(t);
      }
    }
  } else {
    const int vt = wv - 8;
    bf16x8 Bv[4];
#pragma unroll
    for (int kk = 0; kk < 4; ++kk) Bv[kk] = wq(16 + vt, kk);
    const float bv_ = bias[2 * CDIM + vt * 16 + lm];
    for (int mi = 0; mi < 7; ++mi) {
      int arow = mi * 16 + lm; if (arow > 97) arow = 97;
      bf16x8 A[4];
#pragma unroll
      for (int kk = 0; kk < 4; ++kk) A[kk] = *(const bf16x8*)&xs[swzK(arow, kk * 32 + lg * 8)];
      f32x4 av = {0.f,0.f,0.f,0.f};
#pragma unroll
      for (int kk = 0; kk < 4; ++kk) av = MFMA32(A[kk], Bv[kk], av);  // normal: row=tok, col=chan
      int vtok0 = mi * 16 + lg * 4;
      if (vtok0 < 100) {                             // cols 98..99 get finite pad data
        f32x4 t;
#pragma unroll
        for (int r = 0; r < 4; ++r) t[r] = av[r] + bv_;
        *(bf16x4*)&vbuf[(size_t)(vt * 16 + lm) * 100 + vtok0] = cvt4(t);
      }
    }
  }

  // ---- one attention unit per wave: unit wv = (hh, mi), hh = wv/7, mi = wv%7 ----
  const bool active = (wv < 14);
  const int hh = wv / 7, mi = wv % 7;

  // q (swapped): lane holds q[chan][tok=lm] as B-frags for MFMA16 QK^T
  bf16x4 bq[2][2];                                   // [g][ct]
  if (active) {
    int arow = mi * 16 + lm; if (arow > 97) arow = 97;
    bf16x8 Xf[4];
#pragma unroll
    for (int kk = 0; kk < 4; ++kk) Xf[kk] = *(const bf16x8*)&xs[swzK(arow, kk * 32 + lg * 8)];
#pragma unroll
    for (int g = 0; g < 2; ++g) {
      const int h = 2 * g + hh;
#pragma unroll
      for (int ct = 0; ct < 2; ++ct) {
        const int t = h * 2 + ct;                    // q row-tile
        f32x4 acc = {0.f,0.f,0.f,0.f};
#pragma unroll
        for (int kk = 0; kk < 4; ++kk) acc = MFMA32(wq(t, kk), Xf[kk], acc);
        const float4 qb4 = *(const float4*)(bias + t * 16 + lg * 4);
        f32x4 tq;
#pragma unroll
        for (int r = 0; r < 4; ++r) {
          float vq = acc[r] + ((const float*)&qb4)[r];
          if constexpr (!PRE) vq *= SCALE * LOG2E;
          tq[r] = vq;
        }
        bq[g][ct] = cvt4(tq);
      }
    }
  }
  __syncthreads();   // xs reads done (o overlay ok); kbuf/vbuf ready (read-only now)

  // ---------------- attention: 2 units per wave (g=0,1), o -> xs overlay ----------------
#pragma unroll
  for (int g = 0; g < 2; ++g) {
    if (active) {
      const int h = 2 * g + hh, cb = h * 32;
      f32x4 s[7];
      __builtin_amdgcn_s_setprio(1);
#pragma unroll
      for (int nj = 0; nj < 7; ++nj) {               // QK^T swapped: col=m(lm), row=n
        int krow = nj * 16 + lm; if (krow > 97) krow = 97;
        bf16x4 k0 = *(const bf16x4*)&kbuf[swzK(krow, cb + lg * 4)];
        bf16x4 k1 = *(const bf16x4*)&kbuf[swzK(krow, cb + 16 + lg * 4)];
        f32x4 z = {0.f,0.f,0.f,0.f};
        z = MFMA16(k0, bq[g][0], z);
        s[nj] = MFMA16(k1, bq[g][1], z);
      }
      __builtin_amdgcn_s_setprio(0);
      const int m = mi * 16 + lm;
      const int mclamp = m > 97 ? 97 : m;
      float sum;
      if constexpr (PRE) {
        const float* __restrict__ cp =
            cmb + ((size_t)(wmod * 4 + h) * NTOK + mclamp) * CMBW + lg * 4;
        float4 cv[7];                                // MLP: 7 loads in flight together
#pragma unroll
        for (int nj = 0; nj < 7; ++nj) cv[nj] = *(const float4*)(cp + nj * 16);
        float s0 = 0.f, s1 = 0.f, s2 = 0.f, s3 = 0.f;  // 4-way sum split
#pragma unroll
        for (int nj = 0; nj < 7; ++nj) {
          float e0 = EXP2F(s[nj][0] + cv[nj].x);
          float e1 = EXP2F(s[nj][1] + cv[nj].y);
          float e2 = EXP2F(s[nj][2] + cv[nj].z);
          float e3 = EXP2F(s[nj][3] + cv[nj].w);
          s[nj][0] = e0; s[nj][1] = e1; s[nj][2] = e2; s[nj][3] = e3;
          s0 += e0; s1 += e1; s2 += e2; s3 += e3;
        }
        sum = (s0 + s1) + (s2 + s3);
      } else {
        const int cm4 = ((int)mcode[mclamp]) * 4 + h + 1012;
        const float* __restrict__ mrow = maskw + mclamp * NTOK;
        sum = 0.f;
#pragma unroll
        for (int nj = 0; nj < 7; ++nj) {
          const int n0 = nj * 16 + lg * 4;
#pragma unroll
          for (int r = 0; r < 4; ++r) {
            int n = n0 + r;
            float val = NEG_BIG;
            if (n < NTOK)
              val = s[nj][r] + (mrow[n] + bf2f(rpbL[cm4 - ((int)mcode[n]) * 4])) * LOG2E;
            float e = EXP2F(val);
            s[nj][r] = e; sum += e;
          }
        }
      }
      sum += __shfl_xor(sum, 16);
      sum += __shfl_xor(sum, 32);
      const float inv = RCPF(sum);
      float invr[4];                                 // inv for output row lg*4+r
#pragma unroll
      for (int r = 0; r < 4; ++r) invr[r] = __shfl(inv, lg * 4 + r);
      bf16x4 pp[7];                                  // unnormalized P A-frags
#pragma unroll
      for (int nj = 0; nj < 7; ++nj) pp[nj] = cvt4(s[nj]);
      // PV: out[m][d], d = cb + dt*16 + lm; writes into xs overlay
#pragma unroll
      for (int dt = 0; dt < 2; ++dt) {
        const int d = cb + dt * 16 + lm;
        bf16x4 bv[7];                                // MLP: preload LDS B-frags
#pragma unroll
        for (int nj = 0; nj < 7; ++nj) {
          const int vc = nj < 6 ? nj * 16 + lg * 4 : 96;     // clamp: P=0 there
          bv[nj] = *(const bf16x4*)&vbuf[(size_t)d * 100 + vc];
        }
        f32x4 acc = {0.f,0.f,0.f,0.f};
        __builtin_amdgcn_s_setprio(1);
#pragma unroll
        for (int nj = 0; nj < 7; ++nj) acc = MFMA16(pp[nj], bv[nj], acc);
        __builtin_amdgcn_s_setprio(0);
#pragma unroll
        for (int r = 0; r < 4; ++r) {
          int m2 = mi * 16 + lg * 4 + r;
          if (PRE || m2 < NTOK) xs[swzK(m2, d)] = f2bf(acc[r] * invr[r]);
        }
      }
    }
  }
  __syncthreads();   // o complete

  // ---------------- GEMM3 (swapped): out = o @ Wp^T, float4 stores ----------------
  // 8 col-tiles x 7 mi over 16 waves: wave wv -> tile (wv&7), mi in (wv<8 ? 0..3 : 4..6)
  {
    const int ct8 = wv & 7;
    bf16x8 Bp[4];
#pragma unroll
    for (int kk = 0; kk < 4; ++kk) {
      if constexpr (PRE) Bp[kk] = *(const bf16x8*)&ppre[(size_t)((ct8 * 4 + kk) * 64 + lane) * 8];
      else Bp[kk] = ldfrag(proj_w + (size_t)(ct8 * 16 + lm) * CDIM + kk * 32 + lg * 8);
    }
    const float4 pb4 = *(const float4*)((PRE ? bpre + 384 : proj_b) + ct8 * 16 + lg * 4);
    float* __restrict__ outb = out + (size_t)blk * (NTOK * CDIM);
    const int mlo = wv < 8 ? 0 : 4, mhi = wv < 8 ? 4 : 7;
    for (int mi2 = mlo; mi2 < mhi; ++mi2) {
      int orow = mi2 * 16 + lm;
      if (!PRE && orow > 97) orow = 97;
      f32x4 acc = {0.f,0.f,0.f,0.f};
#pragma unroll
      for (int kk = 0; kk < 4; ++kk) {
        bf16x8 Bo = *(const bf16x8*)&xs[swzK(orow, kk * 32 + lg * 8)];
        acc = MFMA32(Bp[kk], Bo, acc);               // row=out-chan, col=token
      }
      int tok = mi2 * 16 + lm;
      if (tok < NTOK) {
        float4 o4;
        o4.x = acc[0] + pb4.x; o4.y = acc[1] + pb4.y;
        o4.z = acc[2] + pb4.z; o4.w = acc[3] + pb4.w;
        *(float4*)(outb + (size_t)tok * CDIM + ct8 * 16 + lg * 4) = o4;
      }
    }
  }
}

extern "C" void kernel_launch(void* const* d_in, const int* in_sizes, int n_in,
                              void* d_out, int out_size, void* d_ws, size_t ws_size,
                              hipStream_t stream) {
  const float* x      = (const float*)d_in[0];
  const float* mask   = (const float*)d_in[1];
  const float* qkv_w  = (const float*)d_in[2];
  const float* qkv_b  = (const float*)d_in[3];
  const float* rpb    = (const float*)d_in[4];
  const float* proj_w = (const float*)d_in[5];
  const float* proj_b = (const float*)d_in[6];
  int B  = in_sizes[0] / (NTOK * CDIM);
  int nW = in_sizes[1] / (NTOK * NTOK);

  const size_t CMB_B  = (size_t)256 * NTOK * CMBW * 4;  // 11,239,424
  const size_t QPRE_B = 24 * 4 * 64 * 8 * 2;            // 98,304
  const size_t PPRE_B = 8 * 4 * 64 * 8 * 2;             // 32,768
  const size_t BIAS_B = 512 * 4;
  const size_t need = CMB_B + QPRE_B + PPRE_B + BIAS_B;

  if (ws_size >= need) {
    float* cmb = (float*)d_ws;
    unsigned short* qpre = (unsigned short*)((char*)d_ws + CMB_B);
    unsigned short* ppre = (unsigned short*)((char*)d_ws + CMB_B + QPRE_B);
    float* bpre = (float*)((char*)d_ws + CMB_B + QPRE_B + PPRE_B);
    hipLaunchKernelGGL(prep_w, dim3(17), dim3(512), 0, stream,
                       qkv_w, qkv_b, proj_w, proj_b, qpre, ppre, bpre);
    hipLaunchKernelGGL(prep_cmb, dim3(1024), dim3(256), 0, stream, mask, rpb, cmb, nW);
    hipLaunchKernelGGL(win_attn<true>, dim3(B), dim3(1024), 0, stream,
                       x, mask, qkv_w, qkv_b, rpb, proj_w, proj_b, (float*)d_out, nW,
                       cmb, qpre, ppre, bpre);
  } else {
    hipLaunchKernelGGL(win_attn<false>, dim3(B), dim3(1024), 0, stream,
                       x, mask, qkv_w, qkv_b, rpb, proj_w, proj_b, (float*)d_out, nW,
                       (const float*)nullptr, (const unsigned short*)nullptr,
                       (const unsigned short*)nullptr, (const float*)nullptr);
  }
}

// Round 17
// 118.850 us; speedup vs baseline: 1.5759x; 1.0651x over previous
//
#include <hip/hip_runtime.h>
#include <hip/hip_bf16.h>

#define NTOK 98
#define CDIM 128
#define SCALE 0.17677669529663687f
#define LOG2E 1.4426950408889634f
#define NEG_BIG -1e30f
#define CMBW 112   // cmb row width: covers full fragment n-range 0..111

typedef short bf16x8 __attribute__((ext_vector_type(8)));
typedef short bf16x4 __attribute__((ext_vector_type(4)));
typedef float f32x4 __attribute__((ext_vector_type(4)));

#define MFMA32(a,b,c) __builtin_amdgcn_mfma_f32_16x16x32_bf16(a,b,c,0,0,0)

#if __has_builtin(__builtin_amdgcn_mfma_f32_16x16x16_bf16)
#define MFMA16(a,b,c) __builtin_amdgcn_mfma_f32_16x16x16_bf16(a,b,c,0,0,0)
#elif __has_builtin(__builtin_amdgcn_mfma_f32_16x16x16bf16_1k)
#define MFMA16(a,b,c) __builtin_amdgcn_mfma_f32_16x16x16bf16_1k(a,b,c,0,0,0)
#else
__device__ __forceinline__ f32x4 mfma16_asm(bf16x4 a, bf16x4 b, f32x4 c) {
  asm("v_mfma_f32_16x16x16_bf16 %0, %1, %2, %0" : "+v"(c) : "v"(a), "v"(b));
  return c;
}
#define MFMA16(a,b,c) mfma16_asm(a,b,c)
#endif

#if __has_builtin(__builtin_amdgcn_exp2f)
#define EXP2F(x) __builtin_amdgcn_exp2f(x)
#else
#define EXP2F(x) exp2f(x)
#endif
#if __has_builtin(__builtin_amdgcn_rcpf)
#define RCPF(x) __builtin_amdgcn_rcpf(x)
#else
#define RCPF(x) (1.f / (x))
#endif

__device__ __forceinline__ unsigned short f2bf(float f) {
  __hip_bfloat16 h = __float2bfloat16(f);
  unsigned short u;
  __builtin_memcpy(&u, &h, 2);
  return u;
}
__device__ __forceinline__ float bf2f(unsigned short b) {
  union { unsigned u; float f; } v; v.u = ((unsigned)b) << 16; return v.f;
}
// 4x f32 -> bf16x4 via packed cvt pairs (memcpy: __hip_bfloat162 not trivially copyable)
__device__ __forceinline__ bf16x4 cvt4(f32x4 v) {
  __hip_bfloat162 a = __float22bfloat162_rn(make_float2(v[0], v[1]));
  __hip_bfloat162 b = __float22bfloat162_rn(make_float2(v[2], v[3]));
  bf16x4 r;
  __builtin_memcpy(&r, &a, 4);
  __builtin_memcpy(((char*)&r) + 4, &b, 4);
  return r;
}

// stride-128 LDS tiles: XOR elem bits 3..5 by row -> b64/b128-safe, kills the
// 256B-stride bank conflict (G4/T2).
__device__ __forceinline__ int swzK(int row, int col) {
  return row * 128 + (col ^ ((row & 7) << 3));
}

__device__ __forceinline__ bf16x8 ldfrag(const float* __restrict__ p) {
  float4 a = *(const float4*)p;
  float4 b = *(const float4*)(p + 4);
  bf16x8 fr;
  fr[0]=(short)f2bf(a.x); fr[1]=(short)f2bf(a.y); fr[2]=(short)f2bf(a.z); fr[3]=(short)f2bf(a.w);
  fr[4]=(short)f2bf(b.x); fr[5]=(short)f2bf(b.y); fr[6]=(short)f2bf(b.z); fr[7]=(short)f2bf(b.w);
  return fr;
}

__device__ __forceinline__ int pcode(int t) {       // rel-pos code
  int d = t / 49, r = t % 49;
  return d * 169 + (r / 7) * 13 + (r % 7);
}

// ---------------- prep 1: weights -> bf16 fragment-order (q: SCALE*LOG2E folded) ----------------
__global__ __launch_bounds__(512)
void prep_w(const float* __restrict__ qkv_w, const float* __restrict__ qkv_b,
            const float* __restrict__ proj_w, const float* __restrict__ proj_b,
            unsigned short* __restrict__ qpre, unsigned short* __restrict__ ppre,
            float* __restrict__ bpre)
{
  int gid = blockIdx.x * 512 + threadIdx.x;
  if (gid < 6144) {                                  // qkv: 24 row-tiles x 4 kk x 64 lanes
    int t = gid >> 8, rem = gid & 255, kk = rem >> 6, ln = rem & 63;
    int row = t * 16 + (ln & 15), col = kk * 32 + (ln >> 4) * 8;
    float sc = (row < CDIM) ? SCALE * LOG2E : 1.f;   // fold scale*log2e into Wq
    const float* s = qkv_w + (size_t)row * CDIM + col;
    unsigned short* d = qpre + (size_t)gid * 8;
#pragma unroll
    for (int e = 0; e < 8; ++e) d[e] = f2bf(s[e] * sc);
  } else if (gid < 8192) {                           // proj: 8 row-tiles
    int f2 = gid - 6144;
    int t = f2 >> 8, rem = f2 & 255, kk = rem >> 6, ln = rem & 63;
    const float* s = proj_w + (size_t)(t * 16 + (ln & 15)) * CDIM + kk * 32 + (ln >> 4) * 8;
    unsigned short* d = ppre + (size_t)f2 * 8;
#pragma unroll
    for (int e = 0; e < 8; ++e) d[e] = f2bf(s[e]);
  } else {                                           // biases (512 values)
    int i = gid - 8192;
    if (i < 384) bpre[i] = qkv_b[i] * (i < CDIM ? SCALE * LOG2E : 1.f);
    else if (i < 512) bpre[i] = proj_b[i - 384];
  }
}

// ---------------- prep 2: cmb[w][h][m][0..111] = (mask + rpb)*LOG2E (pads = -1e30) ----------------
__global__ __launch_bounds__(256)
void prep_cmb(const float* __restrict__ mask, const float* __restrict__ rpb,
              float* __restrict__ cmb, int nW)
{
  const int total = 256 * NTOK * CMBW;               // (w,h) x m x n-padded
  for (int idx = blockIdx.x * 256 + threadIdx.x; idx < total; idx += gridDim.x * 256) {
    int row = idx / CMBW, n = idx - row * CMBW;
    int wh = row / NTOK, m = row - wh * NTOK;
    int w = wh >> 2, h = wh & 3;
    float v = NEG_BIG;
    if (n < NTOK)
      v = (mask[((size_t)w * NTOK + m) * NTOK + n]
           + rpb[(pcode(m) - pcode(n) + 253) * 4 + h]) * LOG2E;
    cmb[idx] = v;
  }
}

// ---------------- main kernel ----------------
// R17 = R15 (1024-thread, 81% occupancy) + (1) flattened 28-unit attention
// schedule (R15 idled waves 14-15 through attention; now 12 waves x 2 units +
// 4 waves x 1, every wave contributes to the latency-hiding pool) and (2)
// 4-way softmax sum split (pure reassociation). R16's register preloads
// removed (VGPR-budget overflow -> scratch, no gain).
template<bool PRE>
__global__ __launch_bounds__(1024, 8)
void win_attn(const float* __restrict__ x, const float* __restrict__ mask,
              const float* __restrict__ qkv_w, const float* __restrict__ qkv_b,
              const float* __restrict__ rpb, const float* __restrict__ proj_w,
              const float* __restrict__ proj_b, float* __restrict__ out, int nW,
              const float* __restrict__ cmb, const unsigned short* __restrict__ qpre,
              const unsigned short* __restrict__ ppre, const float* __restrict__ bpre)
{
  __shared__ __align__(16) unsigned short xs[(PRE ? 112 : 98) * 128]; // x; later o
  __shared__ __align__(16) unsigned short kbuf[98 * 128];             // k [tok][chan] (swapped)
  __shared__ __align__(16) unsigned short vbuf[128 * 100];            // v^T [chan][tok]
  __shared__ unsigned short rpbL[PRE ? 2 : 2028];
  __shared__ short mcode[PRE ? 2 : 112];

  const int tid = threadIdx.x;
  const int lane = tid & 63;
  const int wv = tid >> 6;                           // wave 0..15
  const int lm = lane & 15;
  const int lg = lane >> 4;
  const int blk = blockIdx.x;
  const int wmod = blk % nW;
  const float* __restrict__ xblk = x + (size_t)blk * (NTOK * CDIM);
  const float* __restrict__ maskw = mask + (size_t)wmod * (NTOK * NTOK);
  const float* __restrict__ bias = PRE ? bpre : qkv_b;

  if constexpr (!PRE) {
    if (tid < 112) mcode[tid] = (short)(tid < NTOK ? pcode(tid) : 0);
    for (int i = tid; i < 2028; i += 1024) rpbL[i] = f2bf(rpb[i]);
  }
  for (int v = tid; v < NTOK * 32; v += 1024) {      // stage x -> xs (bf16, swizzled)
    int row = v >> 5, c4 = (v & 31) << 2;
    float4 f = *(const float4*)(xblk + row * CDIM + c4);
    f32x4 fv; fv[0]=f.x; fv[1]=f.y; fv[2]=f.z; fv[3]=f.w;
    *(bf16x4*)&xs[swzK(row, c4)] = cvt4(fv);
  }
  __syncthreads();

  // weight fragment accessors
  auto wq = [&](int t, int kk) -> bf16x8 {           // qkv rows (t<8: q pre-scaled)
    if constexpr (PRE) return *(const bf16x8*)&qpre[(size_t)((t * 4 + kk) * 64 + lane) * 8];
    else return ldfrag(qkv_w + (size_t)(t * 16 + lm) * CDIM + kk * 32 + lg * 8);
  };

  // ---------------- prologue: waves 0-7 -> k tile wv (swapped); 8-15 -> v tile wv-8 ----------------
  if (wv < 8) {
    bf16x8 Bk[4];
#pragma unroll
    for (int kk = 0; kk < 4; ++kk) Bk[kk] = wq(8 + wv, kk);
    const float4 bk4 = *(const float4*)(bias + CDIM + wv * 16 + lg * 4);
    for (int mi = 0; mi < 7; ++mi) {
      int arow = mi * 16 + lm; if (arow > 97) arow = 97;
      bf16x8 A[4];
#pragma unroll
      for (int kk = 0; kk < 4; ++kk) A[kk] = *(const bf16x8*)&xs[swzK(arow, kk * 32 + lg * 8)];
      f32x4 ak = {0.f,0.f,0.f,0.f};
#pragma unroll
      for (int kk = 0; kk < 4; ++kk) ak = MFMA32(Bk[kk], A[kk], ak);  // swapped: row=chan, col=tok
      int ktok = mi * 16 + lm;
      if (ktok < NTOK) {
        f32x4 t;
#pragma unroll
        for (int r = 0; r < 4; ++r) t[r] = ak[r] + ((const float*)&bk4)[r];
        *(bf16x4*)&kbuf[swzK(ktok, wv * 16 + lg * 4)] = cvt4(t);
      }
    }
  } else {
    const int vt = wv - 8;
    bf16x8 Bv[4];
#pragma unroll
    for (int kk = 0; kk < 4; ++kk) Bv[kk] = wq(16 + vt, kk);
    const float bv_ = bias[2 * CDIM + vt * 16 + lm];
    for (int mi = 0; mi < 7; ++mi) {
      int arow = mi * 16 + lm; if (arow > 97) arow = 97;
      bf16x8 A[4];
#pragma unroll
      for (int kk = 0; kk < 4; ++kk) A[kk] = *(const bf16x8*)&xs[swzK(arow, kk * 32 + lg * 8)];
      f32x4 av = {0.f,0.f,0.f,0.f};
#pragma unroll
      for (int kk = 0; kk < 4; ++kk) av = MFMA32(A[kk], Bv[kk], av);  // normal: row=tok, col=chan
      int vtok0 = mi * 16 + lg * 4;
      if (vtok0 < 100) {                             // cols 98..99 get finite pad data
        f32x4 t;
#pragma unroll
        for (int r = 0; r < 4; ++r) t[r] = av[r] + bv_;
        *(bf16x4*)&vbuf[(size_t)(vt * 16 + lm) * 100 + vtok0] = cvt4(t);
      }
    }
  }

  // ---- flattened unit schedule: unit u = wv + 16*p, p in {0,1}; u < 28 ----
  // u -> (g = u/14, hh = (u%14)/7, mi = u%7); h = 2g + hh.  (14 = 2*7 so
  // (u%14)%7 == u%7.)  Pass 0: all 16 waves; pass 1: waves 0..11.
  // q (swapped): lane holds q[chan][tok=lm] as B-frags for MFMA16 QK^T.
  bf16x4 bq[2][2];                                   // [pass][ct]
#pragma unroll
  for (int p = 0; p < 2; ++p) {
    const int u = wv + 16 * p;
    if (u < 28) {
      const int g = u / 14, hh = (u % 14) / 7, mi = u % 7;
      const int h = 2 * g + hh;
      int arow = mi * 16 + lm; if (arow > 97) arow = 97;
      bf16x8 Xf[4];
#pragma unroll
      for (int kk = 0; kk < 4; ++kk) Xf[kk] = *(const bf16x8*)&xs[swzK(arow, kk * 32 + lg * 8)];
#pragma unroll
      for (int ct = 0; ct < 2; ++ct) {
        const int t = h * 2 + ct;                    // q row-tile
        f32x4 acc = {0.f,0.f,0.f,0.f};
#pragma unroll
        for (int kk = 0; kk < 4; ++kk) acc = MFMA32(wq(t, kk), Xf[kk], acc);
        const float4 qb4 = *(const float4*)(bias + t * 16 + lg * 4);
        f32x4 tq;
#pragma unroll
        for (int r = 0; r < 4; ++r) {
          float vq = acc[r] + ((const float*)&qb4)[r];
          if constexpr (!PRE) vq *= SCALE * LOG2E;
          tq[r] = vq;
        }
        bq[p][ct] = cvt4(tq);
      }
    }
  }
  __syncthreads();   // xs reads done (o overlay ok); kbuf/vbuf ready (read-only now)

  // ---------------- attention: units u = wv, wv+16 (o -> xs overlay) ----------------
#pragma unroll
  for (int p = 0; p < 2; ++p) {
    const int u = wv + 16 * p;
    if (u < 28) {
      const int g = u / 14, hh = (u % 14) / 7, mi = u % 7;
      const int h = 2 * g + hh, cb = h * 32;
      f32x4 s[7];
      __builtin_amdgcn_s_setprio(1);
#pragma unroll
      for (int nj = 0; nj < 7; ++nj) {               // QK^T swapped: col=m(lm), row=n
        int krow = nj * 16 + lm; if (krow > 97) krow = 97;
        bf16x4 k0 = *(const bf16x4*)&kbuf[swzK(krow, cb + lg * 4)];
        bf16x4 k1 = *(const bf16x4*)&kbuf[swzK(krow, cb + 16 + lg * 4)];
        f32x4 z = {0.f,0.f,0.f,0.f};
        z = MFMA16(k0, bq[p][0], z);
        s[nj] = MFMA16(k1, bq[p][1], z);
      }
      __builtin_amdgcn_s_setprio(0);
      const int m = mi * 16 + lm;
      const int mclamp = m > 97 ? 97 : m;
      float sum;
      if constexpr (PRE) {
        const float* __restrict__ cp =
            cmb + ((size_t)(wmod * 4 + h) * NTOK + mclamp) * CMBW + lg * 4;
        float s0 = 0.f, s1 = 0.f, s2 = 0.f, s3 = 0.f;  // 4-way sum split
#pragma unroll
        for (int nj = 0; nj < 7; ++nj) {
          float4 cv = *(const float4*)(cp + nj * 16);
          float e0 = EXP2F(s[nj][0] + cv.x);
          float e1 = EXP2F(s[nj][1] + cv.y);
          float e2 = EXP2F(s[nj][2] + cv.z);
          float e3 = EXP2F(s[nj][3] + cv.w);
          s[nj][0] = e0; s[nj][1] = e1; s[nj][2] = e2; s[nj][3] = e3;
          s0 += e0; s1 += e1; s2 += e2; s3 += e3;
        }
        sum = (s0 + s1) + (s2 + s3);
      } else {
        const int cm4 = ((int)mcode[mclamp]) * 4 + h + 1012;
        const float* __restrict__ mrow = maskw + mclamp * NTOK;
        sum = 0.f;
#pragma unroll
        for (int nj = 0; nj < 7; ++nj) {
          const int n0 = nj * 16 + lg * 4;
#pragma unroll
          for (int r = 0; r < 4; ++r) {
            int n = n0 + r;
            float val = NEG_BIG;
            if (n < NTOK)
              val = s[nj][r] + (mrow[n] + bf2f(rpbL[cm4 - ((int)mcode[n]) * 4])) * LOG2E;
            float e = EXP2F(val);
            s[nj][r] = e; sum += e;
          }
        }
      }
      sum += __shfl_xor(sum, 16);
      sum += __shfl_xor(sum, 32);
      const float inv = RCPF(sum);
      float invr[4];                                 // inv for output row lg*4+r
#pragma unroll
      for (int r = 0; r < 4; ++r) invr[r] = __shfl(inv, lg * 4 + r);
      bf16x4 pp[7];                                  // unnormalized P A-frags
#pragma unroll
      for (int nj = 0; nj < 7; ++nj) pp[nj] = cvt4(s[nj]);
      // PV: out[m][d], d = cb + dt*16 + lm; writes into xs overlay
#pragma unroll
      for (int dt = 0; dt < 2; ++dt) {
        const int d = cb + dt * 16 + lm;
        f32x4 acc = {0.f,0.f,0.f,0.f};
        __builtin_amdgcn_s_setprio(1);
#pragma unroll
        for (int nj = 0; nj < 7; ++nj) {
          const int vc = nj < 6 ? nj * 16 + lg * 4 : 96;     // clamp: P=0 there
          bf16x4 bv = *(const bf16x4*)&vbuf[(size_t)d * 100 + vc];
          acc = MFMA16(pp[nj], bv, acc);
        }
        __builtin_amdgcn_s_setprio(0);
#pragma unroll
        for (int r = 0; r < 4; ++r) {
          int m2 = mi * 16 + lg * 4 + r;
          if (PRE || m2 < NTOK) xs[swzK(m2, d)] = f2bf(acc[r] * invr[r]);
        }
      }
    }
  }
  __syncthreads();   // o complete

  // ---------------- GEMM3 (swapped): out = o @ Wp^T, float4 stores ----------------
  // 8 col-tiles x 7 mi over 16 waves: wave wv -> tile (wv&7), mi in (wv<8 ? 0..3 : 4..6)
  {
    const int ct8 = wv & 7;
    bf16x8 Bp[4];
#pragma unroll
    for (int kk = 0; kk < 4; ++kk) {
      if constexpr (PRE) Bp[kk] = *(const bf16x8*)&ppre[(size_t)((ct8 * 4 + kk) * 64 + lane) * 8];
      else Bp[kk] = ldfrag(proj_w + (size_t)(ct8 * 16 + lm) * CDIM + kk * 32 + lg * 8);
    }
    const float4 pb4 = *(const float4*)((PRE ? bpre + 384 : proj_b) + ct8 * 16 + lg * 4);
    float* __restrict__ outb = out + (size_t)blk * (NTOK * CDIM);
    const int mlo = wv < 8 ? 0 : 4, mhi = wv < 8 ? 4 : 7;
    for (int mi2 = mlo; mi2 < mhi; ++mi2) {
      int orow = mi2 * 16 + lm;
      if (!PRE && orow > 97) orow = 97;
      f32x4 acc = {0.f,0.f,0.f,0.f};
#pragma unroll
      for (int kk = 0; kk < 4; ++kk) {
        bf16x8 Bo = *(const bf16x8*)&xs[swzK(orow, kk * 32 + lg * 8)];
        acc = MFMA32(Bp[kk], Bo, acc);               // row=out-chan, col=token
      }
      int tok = mi2 * 16 + lm;
      if (tok < NTOK) {
        float4 o4;
        o4.x = acc[0] + pb4.x; o4.y = acc[1] + pb4.y;
        o4.z = acc[2] + pb4.z; o4.w = acc[3] + pb4.w;
        *(float4*)(outb + (size_t)tok * CDIM + ct8 * 16 + lg * 4) = o4;
      }
    }
  }
}

extern "C" void kernel_launch(void* const* d_in, const int* in_sizes, int n_in,
                              void* d_out, int out_size, void* d_ws, size_t ws_size,
                              hipStream_t stream) {
  const float* x      = (const float*)d_in[0];
  const float* mask   = (const float*)d_in[1];
  const float* qkv_w  = (const float*)d_in[2];
  const float* qkv_b  = (const float*)d_in[3];
  const float* rpb    = (const float*)d_in[4];
  const float* proj_w = (const float*)d_in[5];
  const float* proj_b = (const float*)d_in[6];
  int B  = in_sizes[0] / (NTOK * CDIM);
  int nW = in_sizes[1] / (NTOK * NTOK);

  const size_t CMB_B  = (size_t)256 * NTOK * CMBW * 4;  // 11,239,424
  const size_t QPRE_B = 24 * 4 * 64 * 8 * 2;            // 98,304
  const size_t PPRE_B = 8 * 4 * 64 * 8 * 2;             // 32,768
  const size_t BIAS_B = 512 * 4;
  const size_t need = CMB_B + QPRE_B + PPRE_B + BIAS_B;

  if (ws_size >= need) {
    float* cmb = (float*)d_ws;
    unsigned short* qpre = (unsigned short*)((char*)d_ws + CMB_B);
    unsigned short* ppre = (unsigned short*)((char*)d_ws + CMB_B + QPRE_B);
    float* bpre = (float*)((char*)d_ws + CMB_B + QPRE_B + PPRE_B);
    hipLaunchKernelGGL(prep_w, dim3(17), dim3(512), 0, stream,
                       qkv_w, qkv_b, proj_w, proj_b, qpre, ppre, bpre);
    hipLaunchKernelGGL(prep_cmb, dim3(1024), dim3(256), 0, stream, mask, rpb, cmb, nW);
    hipLaunchKernelGGL(win_attn<true>, dim3(B), dim3(1024), 0, stream,
                       x, mask, qkv_w, qkv_b, rpb, proj_w, proj_b, (float*)d_out, nW,
                       cmb, qpre, ppre, bpre);
  } else {
    hipLaunchKernelGGL(win_attn<false>, dim3(B), dim3(1024), 0, stream,
                       x, mask, qkv_w, qkv_b, rpb, proj_w, proj_b, (float*)d_out, nW,
                       (const float*)nullptr, (const unsigned short*)nullptr,
                       (const unsigned short*)nullptr, (const float*)nullptr);
  }
}

// Round 18
// 114.678 us; speedup vs baseline: 1.6333x; 1.0364x over previous
//
#include <hip/hip_runtime.h>
#include <hip/hip_bf16.h>

#define NTOK 98
#define CDIM 128
#define SCALE 0.17677669529663687f
#define LOG2E 1.4426950408889634f
#define NEG_BIG -1e30f
#define CMBW 112   // cmb row width: covers full fragment n-range 0..111

typedef short bf16x8 __attribute__((ext_vector_type(8)));
typedef short bf16x4 __attribute__((ext_vector_type(4)));
typedef float f32x4 __attribute__((ext_vector_type(4)));

#define MFMA32(a,b,c) __builtin_amdgcn_mfma_f32_16x16x32_bf16(a,b,c,0,0,0)

#if __has_builtin(__builtin_amdgcn_mfma_f32_16x16x16_bf16)
#define MFMA16(a,b,c) __builtin_amdgcn_mfma_f32_16x16x16_bf16(a,b,c,0,0,0)
#elif __has_builtin(__builtin_amdgcn_mfma_f32_16x16x16bf16_1k)
#define MFMA16(a,b,c) __builtin_amdgcn_mfma_f32_16x16x16bf16_1k(a,b,c,0,0,0)
#else
__device__ __forceinline__ f32x4 mfma16_asm(bf16x4 a, bf16x4 b, f32x4 c) {
  asm("v_mfma_f32_16x16x16_bf16 %0, %1, %2, %0" : "+v"(c) : "v"(a), "v"(b));
  return c;
}
#define MFMA16(a,b,c) mfma16_asm(a,b,c)
#endif

#if __has_builtin(__builtin_amdgcn_exp2f)
#define EXP2F(x) __builtin_amdgcn_exp2f(x)
#else
#define EXP2F(x) exp2f(x)
#endif
#if __has_builtin(__builtin_amdgcn_rcpf)
#define RCPF(x) __builtin_amdgcn_rcpf(x)
#else
#define RCPF(x) (1.f / (x))
#endif

__device__ __forceinline__ unsigned short f2bf(float f) {
  __hip_bfloat16 h = __float2bfloat16(f);
  unsigned short u;
  __builtin_memcpy(&u, &h, 2);
  return u;
}
__device__ __forceinline__ float bf2f(unsigned short b) {
  union { unsigned u; float f; } v; v.u = ((unsigned)b) << 16; return v.f;
}
// 4x f32 -> bf16x4 via packed cvt pairs (memcpy: __hip_bfloat162 not trivially copyable)
__device__ __forceinline__ bf16x4 cvt4(f32x4 v) {
  __hip_bfloat162 a = __float22bfloat162_rn(make_float2(v[0], v[1]));
  __hip_bfloat162 b = __float22bfloat162_rn(make_float2(v[2], v[3]));
  bf16x4 r;
  __builtin_memcpy(&r, &a, 4);
  __builtin_memcpy(((char*)&r) + 4, &b, 4);
  return r;
}

// stride-128 LDS tiles: XOR elem bits 3..5 by row -> b64/b128-safe, kills the
// 256B-stride bank conflict (G4/T2).
__device__ __forceinline__ int swzK(int row, int col) {
  return row * 128 + (col ^ ((row & 7) << 3));
}

__device__ __forceinline__ bf16x8 ldfrag(const float* __restrict__ p) {
  float4 a = *(const float4*)p;
  float4 b = *(const float4*)(p + 4);
  bf16x8 fr;
  fr[0]=(short)f2bf(a.x); fr[1]=(short)f2bf(a.y); fr[2]=(short)f2bf(a.z); fr[3]=(short)f2bf(a.w);
  fr[4]=(short)f2bf(b.x); fr[5]=(short)f2bf(b.y); fr[6]=(short)f2bf(b.z); fr[7]=(short)f2bf(b.w);
  return fr;
}

__device__ __forceinline__ int pcode(int t) {       // rel-pos code
  int d = t / 49, r = t % 49;
  return d * 169 + (r / 7) * 13 + (r % 7);
}

// ---------------- prep 1: weights -> bf16 fragment-order (q: SCALE*LOG2E folded) ----------------
__global__ __launch_bounds__(512)
void prep_w(const float* __restrict__ qkv_w, const float* __restrict__ qkv_b,
            const float* __restrict__ proj_w, const float* __restrict__ proj_b,
            unsigned short* __restrict__ qpre, unsigned short* __restrict__ ppre,
            float* __restrict__ bpre)
{
  int gid = blockIdx.x * 512 + threadIdx.x;
  if (gid < 6144) {                                  // qkv: 24 row-tiles x 4 kk x 64 lanes
    int t = gid >> 8, rem = gid & 255, kk = rem >> 6, ln = rem & 63;
    int row = t * 16 + (ln & 15), col = kk * 32 + (ln >> 4) * 8;
    float sc = (row < CDIM) ? SCALE * LOG2E : 1.f;   // fold scale*log2e into Wq
    const float* s = qkv_w + (size_t)row * CDIM + col;
    unsigned short* d = qpre + (size_t)gid * 8;
#pragma unroll
    for (int e = 0; e < 8; ++e) d[e] = f2bf(s[e] * sc);
  } else if (gid < 8192) {                           // proj: 8 row-tiles
    int f2 = gid - 6144;
    int t = f2 >> 8, rem = f2 & 255, kk = rem >> 6, ln = rem & 63;
    const float* s = proj_w + (size_t)(t * 16 + (ln & 15)) * CDIM + kk * 32 + (ln >> 4) * 8;
    unsigned short* d = ppre + (size_t)f2 * 8;
#pragma unroll
    for (int e = 0; e < 8; ++e) d[e] = f2bf(s[e]);
  } else {                                           // biases (512 values)
    int i = gid - 8192;
    if (i < 384) bpre[i] = qkv_b[i] * (i < CDIM ? SCALE * LOG2E : 1.f);
    else if (i < 512) bpre[i] = proj_b[i - 384];
  }
}

// ---------------- prep 2: cmb[w][h][m][0..111] = (mask + rpb)*LOG2E (pads = -1e30) ----------------
__global__ __launch_bounds__(256)
void prep_cmb(const float* __restrict__ mask, const float* __restrict__ rpb,
              float* __restrict__ cmb, int nW)
{
  const int total = 256 * NTOK * CMBW;               // (w,h) x m x n-padded
  for (int idx = blockIdx.x * 256 + threadIdx.x; idx < total; idx += gridDim.x * 256) {
    int row = idx / CMBW, n = idx - row * CMBW;
    int wh = row / NTOK, m = row - wh * NTOK;
    int w = wh >> 2, h = wh & 3;
    float v = NEG_BIG;
    if (n < NTOK)
      v = (mask[((size_t)w * NTOK + m) * NTOK + n]
           + rpb[(pcode(m) - pcode(n) + 253) * 4 + h]) * LOG2E;
    cmb[idx] = v;
  }
}

// ---------------- main kernel ----------------
// R18 = R17 + PV operand swap: MFMA16(V_frag, P_frag) -- register contents are
// bit-identical (vbuf[chan][tok] IS the V A-frag; pp IS the P B-frag), but the
// output flips to D[row=d][col=m=lm], so (1) normalization uses the lane-local
// inv (drops 4 ds_bpermute shuffles/unit) and (2) each lane owns 4 consecutive
// d -> o-write is one b64 store instead of 4 scalar u16 (16 -> 4 ds_writes/unit).
template<bool PRE>
__global__ __launch_bounds__(1024, 8)
void win_attn(const float* __restrict__ x, const float* __restrict__ mask,
              const float* __restrict__ qkv_w, const float* __restrict__ qkv_b,
              const float* __restrict__ rpb, const float* __restrict__ proj_w,
              const float* __restrict__ proj_b, float* __restrict__ out, int nW,
              const float* __restrict__ cmb, const unsigned short* __restrict__ qpre,
              const unsigned short* __restrict__ ppre, const float* __restrict__ bpre)
{
  __shared__ __align__(16) unsigned short xs[(PRE ? 112 : 98) * 128]; // x; later o
  __shared__ __align__(16) unsigned short kbuf[98 * 128];             // k [tok][chan] (swapped)
  __shared__ __align__(16) unsigned short vbuf[128 * 100];            // v^T [chan][tok]
  __shared__ unsigned short rpbL[PRE ? 2 : 2028];
  __shared__ short mcode[PRE ? 2 : 112];

  const int tid = threadIdx.x;
  const int lane = tid & 63;
  const int wv = tid >> 6;                           // wave 0..15
  const int lm = lane & 15;
  const int lg = lane >> 4;
  const int blk = blockIdx.x;
  const int wmod = blk % nW;
  const float* __restrict__ xblk = x + (size_t)blk * (NTOK * CDIM);
  const float* __restrict__ maskw = mask + (size_t)wmod * (NTOK * NTOK);
  const float* __restrict__ bias = PRE ? bpre : qkv_b;

  if constexpr (!PRE) {
    if (tid < 112) mcode[tid] = (short)(tid < NTOK ? pcode(tid) : 0);
    for (int i = tid; i < 2028; i += 1024) rpbL[i] = f2bf(rpb[i]);
  }
  for (int v = tid; v < NTOK * 32; v += 1024) {      // stage x -> xs (bf16, swizzled)
    int row = v >> 5, c4 = (v & 31) << 2;
    float4 f = *(const float4*)(xblk + row * CDIM + c4);
    f32x4 fv; fv[0]=f.x; fv[1]=f.y; fv[2]=f.z; fv[3]=f.w;
    *(bf16x4*)&xs[swzK(row, c4)] = cvt4(fv);
  }
  __syncthreads();

  // weight fragment accessors
  auto wq = [&](int t, int kk) -> bf16x8 {           // qkv rows (t<8: q pre-scaled)
    if constexpr (PRE) return *(const bf16x8*)&qpre[(size_t)((t * 4 + kk) * 64 + lane) * 8];
    else return ldfrag(qkv_w + (size_t)(t * 16 + lm) * CDIM + kk * 32 + lg * 8);
  };

  // ---------------- prologue: waves 0-7 -> k tile wv (swapped); 8-15 -> v tile wv-8 ----------------
  if (wv < 8) {
    bf16x8 Bk[4];
#pragma unroll
    for (int kk = 0; kk < 4; ++kk) Bk[kk] = wq(8 + wv, kk);
    const float4 bk4 = *(const float4*)(bias + CDIM + wv * 16 + lg * 4);
    for (int mi = 0; mi < 7; ++mi) {
      int arow = mi * 16 + lm; if (arow > 97) arow = 97;
      bf16x8 A[4];
#pragma unroll
      for (int kk = 0; kk < 4; ++kk) A[kk] = *(const bf16x8*)&xs[swzK(arow, kk * 32 + lg * 8)];
      f32x4 ak = {0.f,0.f,0.f,0.f};
#pragma unroll
      for (int kk = 0; kk < 4; ++kk) ak = MFMA32(Bk[kk], A[kk], ak);  // swapped: row=chan, col=tok
      int ktok = mi * 16 + lm;
      if (ktok < NTOK) {
        f32x4 t;
#pragma unroll
        for (int r = 0; r < 4; ++r) t[r] = ak[r] + ((const float*)&bk4)[r];
        *(bf16x4*)&kbuf[swzK(ktok, wv * 16 + lg * 4)] = cvt4(t);
      }
    }
  } else {
    const int vt = wv - 8;
    bf16x8 Bv[4];
#pragma unroll
    for (int kk = 0; kk < 4; ++kk) Bv[kk] = wq(16 + vt, kk);
    const float bv_ = bias[2 * CDIM + vt * 16 + lm];
    for (int mi = 0; mi < 7; ++mi) {
      int arow = mi * 16 + lm; if (arow > 97) arow = 97;
      bf16x8 A[4];
#pragma unroll
      for (int kk = 0; kk < 4; ++kk) A[kk] = *(const bf16x8*)&xs[swzK(arow, kk * 32 + lg * 8)];
      f32x4 av = {0.f,0.f,0.f,0.f};
#pragma unroll
      for (int kk = 0; kk < 4; ++kk) av = MFMA32(A[kk], Bv[kk], av);  // normal: row=tok, col=chan
      int vtok0 = mi * 16 + lg * 4;
      if (vtok0 < 100) {                             // cols 98..99 get finite pad data
        f32x4 t;
#pragma unroll
        for (int r = 0; r < 4; ++r) t[r] = av[r] + bv_;
        *(bf16x4*)&vbuf[(size_t)(vt * 16 + lm) * 100 + vtok0] = cvt4(t);
      }
    }
  }

  // ---- flattened unit schedule: unit u = wv + 16*p, p in {0,1}; u < 28 ----
  // u -> (g = u/14, hh = (u%14)/7, mi = u%7); h = 2g + hh.
  // q (swapped): lane holds q[chan][tok=lm] as B-frags for MFMA16 QK^T.
  bf16x4 bq[2][2];                                   // [pass][ct]
#pragma unroll
  for (int p = 0; p < 2; ++p) {
    const int u = wv + 16 * p;
    if (u < 28) {
      const int g = u / 14, hh = (u % 14) / 7, mi = u % 7;
      const int h = 2 * g + hh;
      int arow = mi * 16 + lm; if (arow > 97) arow = 97;
      bf16x8 Xf[4];
#pragma unroll
      for (int kk = 0; kk < 4; ++kk) Xf[kk] = *(const bf16x8*)&xs[swzK(arow, kk * 32 + lg * 8)];
#pragma unroll
      for (int ct = 0; ct < 2; ++ct) {
        const int t = h * 2 + ct;                    // q row-tile
        f32x4 acc = {0.f,0.f,0.f,0.f};
#pragma unroll
        for (int kk = 0; kk < 4; ++kk) acc = MFMA32(wq(t, kk), Xf[kk], acc);
        const float4 qb4 = *(const float4*)(bias + t * 16 + lg * 4);
        f32x4 tq;
#pragma unroll
        for (int r = 0; r < 4; ++r) {
          float vq = acc[r] + ((const float*)&qb4)[r];
          if constexpr (!PRE) vq *= SCALE * LOG2E;
          tq[r] = vq;
        }
        bq[p][ct] = cvt4(tq);
      }
    }
  }
  __syncthreads();   // xs reads done (o overlay ok); kbuf/vbuf ready (read-only now)

  // ---------------- attention: units u = wv, wv+16 (o -> xs overlay) ----------------
#pragma unroll
  for (int p = 0; p < 2; ++p) {
    const int u = wv + 16 * p;
    if (u < 28) {
      const int g = u / 14, hh = (u % 14) / 7, mi = u % 7;
      const int h = 2 * g + hh, cb = h * 32;
      f32x4 s[7];
      __builtin_amdgcn_s_setprio(1);
#pragma unroll
      for (int nj = 0; nj < 7; ++nj) {               // QK^T swapped: col=m(lm), row=n
        int krow = nj * 16 + lm; if (krow > 97) krow = 97;
        bf16x4 k0 = *(const bf16x4*)&kbuf[swzK(krow, cb + lg * 4)];
        bf16x4 k1 = *(const bf16x4*)&kbuf[swzK(krow, cb + 16 + lg * 4)];
        f32x4 z = {0.f,0.f,0.f,0.f};
        z = MFMA16(k0, bq[p][0], z);
        s[nj] = MFMA16(k1, bq[p][1], z);
      }
      __builtin_amdgcn_s_setprio(0);
      const int m = mi * 16 + lm;
      const int mclamp = m > 97 ? 97 : m;
      float sum;
      if constexpr (PRE) {
        const float* __restrict__ cp =
            cmb + ((size_t)(wmod * 4 + h) * NTOK + mclamp) * CMBW + lg * 4;
        float s0 = 0.f, s1 = 0.f, s2 = 0.f, s3 = 0.f;  // 4-way sum split
#pragma unroll
        for (int nj = 0; nj < 7; ++nj) {
          float4 cv = *(const float4*)(cp + nj * 16);
          float e0 = EXP2F(s[nj][0] + cv.x);
          float e1 = EXP2F(s[nj][1] + cv.y);
          float e2 = EXP2F(s[nj][2] + cv.z);
          float e3 = EXP2F(s[nj][3] + cv.w);
          s[nj][0] = e0; s[nj][1] = e1; s[nj][2] = e2; s[nj][3] = e3;
          s0 += e0; s1 += e1; s2 += e2; s3 += e3;
        }
        sum = (s0 + s1) + (s2 + s3);
      } else {
        const int cm4 = ((int)mcode[mclamp]) * 4 + h + 1012;
        const float* __restrict__ mrow = maskw + mclamp * NTOK;
        sum = 0.f;
#pragma unroll
        for (int nj = 0; nj < 7; ++nj) {
          const int n0 = nj * 16 + lg * 4;
#pragma unroll
          for (int r = 0; r < 4; ++r) {
            int n = n0 + r;
            float val = NEG_BIG;
            if (n < NTOK)
              val = s[nj][r] + (mrow[n] + bf2f(rpbL[cm4 - ((int)mcode[n]) * 4])) * LOG2E;
            float e = EXP2F(val);
            s[nj][r] = e; sum += e;
          }
        }
      }
      sum += __shfl_xor(sum, 16);
      sum += __shfl_xor(sum, 32);
      const float inv = RCPF(sum);                   // lane-local: inv for row m=lm
      bf16x4 pp[7];                                  // unnormalized P B-frags (k=n, col=m=lm)
#pragma unroll
      for (int nj = 0; nj < 7; ++nj) pp[nj] = cvt4(s[nj]);
      // PV swapped: D[row=d][col=m=lm]; lane owns 4 consecutive d -> b64 o-write
#pragma unroll
      for (int dt = 0; dt < 2; ++dt) {
        const int dbase = cb + dt * 16;
        f32x4 acc = {0.f,0.f,0.f,0.f};
        __builtin_amdgcn_s_setprio(1);
#pragma unroll
        for (int nj = 0; nj < 7; ++nj) {
          const int vc = nj < 6 ? nj * 16 + lg * 4 : 96;     // clamp: P=0 there
          bf16x4 av = *(const bf16x4*)&vbuf[(size_t)(dbase + lm) * 100 + vc];  // V A-frag
          acc = MFMA16(av, pp[nj], acc);
        }
        __builtin_amdgcn_s_setprio(0);
        if (PRE || m < NTOK) {
          f32x4 t;
#pragma unroll
          for (int r = 0; r < 4; ++r) t[r] = acc[r] * inv;
          *(bf16x4*)&xs[swzK(m, dbase + lg * 4)] = cvt4(t);  // 4 consecutive d
        }
      }
    }
  }
  __syncthreads();   // o complete

  // ---------------- GEMM3 (swapped): out = o @ Wp^T, float4 stores ----------------
  // 8 col-tiles x 7 mi over 16 waves: wave wv -> tile (wv&7), mi in (wv<8 ? 0..3 : 4..6)
  {
    const int ct8 = wv & 7;
    bf16x8 Bp[4];
#pragma unroll
    for (int kk = 0; kk < 4; ++kk) {
      if constexpr (PRE) Bp[kk] = *(const bf16x8*)&ppre[(size_t)((ct8 * 4 + kk) * 64 + lane) * 8];
      else Bp[kk] = ldfrag(proj_w + (size_t)(ct8 * 16 + lm) * CDIM + kk * 32 + lg * 8);
    }
    const float4 pb4 = *(const float4*)((PRE ? bpre + 384 : proj_b) + ct8 * 16 + lg * 4);
    float* __restrict__ outb = out + (size_t)blk * (NTOK * CDIM);
    const int mlo = wv < 8 ? 0 : 4, mhi = wv < 8 ? 4 : 7;
    for (int mi2 = mlo; mi2 < mhi; ++mi2) {
      int orow = mi2 * 16 + lm;
      if (!PRE && orow > 97) orow = 97;
      f32x4 acc = {0.f,0.f,0.f,0.f};
#pragma unroll
      for (int kk = 0; kk < 4; ++kk) {
        bf16x8 Bo = *(const bf16x8*)&xs[swzK(orow, kk * 32 + lg * 8)];
        acc = MFMA32(Bp[kk], Bo, acc);               // row=out-chan, col=token
      }
      int tok = mi2 * 16 + lm;
      if (tok < NTOK) {
        float4 o4;
        o4.x = acc[0] + pb4.x; o4.y = acc[1] + pb4.y;
        o4.z = acc[2] + pb4.z; o4.w = acc[3] + pb4.w;
        *(float4*)(outb + (size_t)tok * CDIM + ct8 * 16 + lg * 4) = o4;
      }
    }
  }
}

extern "C" void kernel_launch(void* const* d_in, const int* in_sizes, int n_in,
                              void* d_out, int out_size, void* d_ws, size_t ws_size,
                              hipStream_t stream) {
  const float* x      = (const float*)d_in[0];
  const float* mask   = (const float*)d_in[1];
  const float* qkv_w  = (const float*)d_in[2];
  const float* qkv_b  = (const float*)d_in[3];
  const float* rpb    = (const float*)d_in[4];
  const float* proj_w = (const float*)d_in[5];
  const float* proj_b = (const float*)d_in[6];
  int B  = in_sizes[0] / (NTOK * CDIM);
  int nW = in_sizes[1] / (NTOK * NTOK);

  const size_t CMB_B  = (size_t)256 * NTOK * CMBW * 4;  // 11,239,424
  const size_t QPRE_B = 24 * 4 * 64 * 8 * 2;            // 98,304
  const size_t PPRE_B = 8 * 4 * 64 * 8 * 2;             // 32,768
  const size_t BIAS_B = 512 * 4;
  const size_t need = CMB_B + QPRE_B + PPRE_B + BIAS_B;

  if (ws_size >= need) {
    float* cmb = (float*)d_ws;
    unsigned short* qpre = (unsigned short*)((char*)d_ws + CMB_B);
    unsigned short* ppre = (unsigned short*)((char*)d_ws + CMB_B + QPRE_B);
    float* bpre = (float*)((char*)d_ws + CMB_B + QPRE_B + PPRE_B);
    hipLaunchKernelGGL(prep_w, dim3(17), dim3(512), 0, stream,
                       qkv_w, qkv_b, proj_w, proj_b, qpre, ppre, bpre);
    hipLaunchKernelGGL(prep_cmb, dim3(1024), dim3(256), 0, stream, mask, rpb, cmb, nW);
    hipLaunchKernelGGL(win_attn<true>, dim3(B), dim3(1024), 0, stream,
                       x, mask, qkv_w, qkv_b, rpb, proj_w, proj_b, (float*)d_out, nW,
                       cmb, qpre, ppre, bpre);
  } else {
    hipLaunchKernelGGL(win_attn<false>, dim3(B), dim3(1024), 0, stream,
                       x, mask, qkv_w, qkv_b, rpb, proj_w, proj_b, (float*)d_out, nW,
                       (const float*)nullptr, (const unsigned short*)nullptr,
                       (const unsigned short*)nullptr, (const float*)nullptr);
  }
}